// Round 4
// baseline (2270.954 us; speedup 1.0000x reference)
//
#include <hip/hip_runtime.h>
#include <hip/hip_bf16.h>
#include <cstdint>
#include <math.h>

// PathwayGraphEncoder: 3-layer GAT (+self-loops, scatter-softmax) -> mean pool
// -> VAE head with JAX threefry2x32 eps reproduction.
// R3: eps switched to PARTITIONABLE threefry (JAX >=0.4.36 default):
//   per flat i: threefry2x32(key=(0,42), x0=0, x1=i), bits = x0' ^ x1'.

#define N_NODES 50000
#define N_EDGES 800000
#define NEG_SLOPE 0.2f

typedef __hip_bfloat16 bf16;

__device__ __forceinline__ float bf2f(bf16 v){ return __bfloat162float(v); }
__device__ __forceinline__ float leaky(float v){ return v>0.f ? v : NEG_SLOPE*v; }

// ---------------- threefry2x32 (JAX-compatible) ----------------
__device__ __forceinline__ void tf_round(unsigned& x0, unsigned& x1, int r){
  x0 += x1; x1 = (x1<<r)|(x1>>(32-r)); x1 ^= x0;
}
__device__ __forceinline__ void threefry2x32(unsigned k0, unsigned k1, unsigned& x0, unsigned& x1){
  unsigned ks2 = k0 ^ k1 ^ 0x1BD11BDAu;
  x0 += k0; x1 += k1;
  tf_round(x0,x1,13); tf_round(x0,x1,15); tf_round(x0,x1,26); tf_round(x0,x1,6);
  x0 += k1; x1 += ks2 + 1u;
  tf_round(x0,x1,17); tf_round(x0,x1,29); tf_round(x0,x1,16); tf_round(x0,x1,24);
  x0 += ks2; x1 += k0 + 2u;
  tf_round(x0,x1,13); tf_round(x0,x1,15); tf_round(x0,x1,26); tf_round(x0,x1,6);
  x0 += k0; x1 += k1 + 3u;
  tf_round(x0,x1,17); tf_round(x0,x1,29); tf_round(x0,x1,16); tf_round(x0,x1,24);
  x0 += k1; x1 += ks2 + 4u;
  tf_round(x0,x1,13); tf_round(x0,x1,15); tf_round(x0,x1,26); tf_round(x0,x1,6);
  x0 += ks2; x1 += k0 + 5u;
}

// Giles single-precision erfinv (XLA ErfInv32 coefficients)
__device__ __forceinline__ float erfinv_approx(float x){
  float w = -log1pf(-x*x);
  float p;
  if (w < 5.0f){
    w = w - 2.5f;
    p = 2.81022636e-08f;
    p = fmaf(p,w,3.43273939e-07f);
    p = fmaf(p,w,-3.5233877e-06f);
    p = fmaf(p,w,-4.39150654e-06f);
    p = fmaf(p,w,0.00021858087f);
    p = fmaf(p,w,-0.00125372503f);
    p = fmaf(p,w,-0.00417768164f);
    p = fmaf(p,w,0.246640727f);
    p = fmaf(p,w,1.50140941f);
  } else {
    w = sqrtf(w) - 3.0f;
    p = -0.000200214257f;
    p = fmaf(p,w,0.000100950558f);
    p = fmaf(p,w,0.00134934322f);
    p = fmaf(p,w,-0.00367342844f);
    p = fmaf(p,w,0.00573950773f);
    p = fmaf(p,w,-0.0076224613f);
    p = fmaf(p,w,0.00943887047f);
    p = fmaf(p,w,1.00167406f);
    p = fmaf(p,w,2.83297682f);
  }
  return p*x;
}

// ------- GEMM: out[n,:] = in[n,:] @ W  (f32 in (or bf16), f32 W, bf16 out) -------
template<int OUT, bool INBF>
__global__ __launch_bounds__(64) void gemm_kernel(const void* __restrict__ inp,
        const float* __restrict__ W, bf16* __restrict__ out){
  __shared__ float xs[256];
  const int n = blockIdx.x, t = threadIdx.x;
  if constexpr (INBF){
    const bf16* px = (const bf16*)inp + (size_t)n*256;
    #pragma unroll
    for (int k=0;k<4;++k) xs[t+64*k] = bf2f(px[t+64*k]);
  } else {
    const float4 xv = ((const float4*)((const float*)inp + (size_t)n*256))[t];
    xs[4*t+0]=xv.x; xs[4*t+1]=xv.y; xs[4*t+2]=xv.z; xs[4*t+3]=xv.w;
  }
  __syncthreads();
  if constexpr (OUT == 256){
    const float4* Wp = (const float4*)W;   // 64 float4 per W row
    float a0=0.f,a1=0.f,a2=0.f,a3=0.f;
    #pragma unroll 4
    for (int k=0;k<256;++k){
      float x = xs[k];
      float4 wv = Wp[k*64 + t];
      a0 = fmaf(x, wv.x, a0);
      a1 = fmaf(x, wv.y, a1);
      a2 = fmaf(x, wv.z, a2);
      a3 = fmaf(x, wv.w, a3);
    }
    union { bf16 h[4]; uint2 u; } pk;
    pk.h[0]=__float2bfloat16(a0); pk.h[1]=__float2bfloat16(a1);
    pk.h[2]=__float2bfloat16(a2); pk.h[3]=__float2bfloat16(a3);
    ((uint2*)(out + (size_t)n*256))[t] = pk.u;
  } else {
    float acc = 0.f;
    #pragma unroll 4
    for (int k=0;k<256;++k) acc = fmaf(xs[k], W[k*OUT+t], acc);
    out[(size_t)n*OUT + t] = __float2bfloat16(acc);
  }
}

// ---------------- attention coefficients: als/ald [N,H] ----------------
template<int H>
__global__ __launch_bounds__(H*64) void attn_coef_kernel(const bf16* __restrict__ h,
        const float* __restrict__ a_s, const float* __restrict__ a_d,
        float* __restrict__ als, float* __restrict__ ald){
  const int n = blockIdx.x, t = threadIdx.x;
  float hv = bf2f(h[(size_t)n*(H*64) + t]);
  float ps = hv * a_s[t];
  float pd = hv * a_d[t];
  #pragma unroll
  for (int o=32;o>0;o>>=1){ ps += __shfl_xor(ps,o); pd += __shfl_xor(pd,o); }
  if ((t & 63)==0){ int head = t>>6; als[n*H+head]=ps; ald[n*H+head]=pd; }
}

// ---------------- CSR build (by destination, includes self-loops) ----------------
__global__ void set_deg_kernel(int* deg, int N){
  int i = blockIdx.x*blockDim.x+threadIdx.x; if (i<N) deg[i]=1;   // self loop
}
__global__ void count_kernel(const int* __restrict__ ei, int* __restrict__ deg, int E){
  int e = blockIdx.x*blockDim.x+threadIdx.x; if (e<E) atomicAdd(&deg[ei[E+e]], 1);
}
__global__ __launch_bounds__(1024) void scan_kernel(const int* __restrict__ deg,
        int* __restrict__ off, int* __restrict__ cursor, int N){
  __shared__ int sh[1024];
  __shared__ int carry_s;
  int t = threadIdx.x;
  if (t==0) carry_s = 0;
  __syncthreads();
  for (int base=0; base<N; base+=1024){
    int v = (base+t < N)? deg[base+t] : 0;
    sh[t]=v; __syncthreads();
    for (int o=1;o<1024;o<<=1){
      int add = (t>=o)? sh[t-o] : 0;
      __syncthreads();
      sh[t] += add;
      __syncthreads();
    }
    int incl = sh[t];
    int excl = incl - v;
    int carry = carry_s;
    if (base+t < N){ off[base+t]=carry+excl; cursor[base+t]=carry+excl; }
    __syncthreads();
    if (t==1023) carry_s = carry + incl;
    __syncthreads();
  }
  if (t==0) off[N] = carry_s;
}
__global__ void fill_kernel(const int* __restrict__ ei, int* __restrict__ cursor,
        int* __restrict__ csr_src, int E, int N){
  int e = blockIdx.x*blockDim.x+threadIdx.x;
  if (e >= E+N) return;
  int s_ = (e < E) ? ei[e]   : e-E;
  int d_ = (e < E) ? ei[E+e] : e-E;
  int p = atomicAdd(&cursor[d_], 1);
  csr_src[p] = s_;
}

// ------- fused scatter-softmax + aggregate: out[n,:] = sum alpha*h[src,:] + b -------
template<int H, bool ELU>
__global__ __launch_bounds__(H*64) void aggregate_kernel(const bf16* __restrict__ h,
        const float* __restrict__ als, const float* __restrict__ ald,
        const int* __restrict__ off, const int* __restrict__ csr_src,
        const float* __restrict__ bias, bf16* __restrict__ out){
  const int n = blockIdx.x, t = threadIdx.x, head = t>>6;
  const int D = H*64;
  const int p0 = off[n], p1 = off[n+1];
  const float aldn = ald[n*H + head];
  float m = -1e30f;
  for (int p=p0; p<p1; ++p){
    float e = leaky(als[csr_src[p]*H + head] + aldn);
    m = fmaxf(m, e);
  }
  float s = 0.f, acc = 0.f;
  for (int p=p0; p<p1; ++p){
    int src = csr_src[p];
    float e = leaky(als[src*H + head] + aldn);
    float w = expf(e - m);
    s += w;
    acc = fmaf(bf2f(h[(size_t)src*D + t]), w, acc);
  }
  float r = acc/(s + 1e-16f) + bias[t];
  if (ELU) r = (r > 0.f) ? r : expm1f(r);
  out[(size_t)n*D + t] = __float2bfloat16(r);
}

// ---------------- pooling + VAE head ----------------
__global__ __launch_bounds__(64) void pool_kernel(const bf16* __restrict__ h3,
        const int* __restrict__ batch, float* __restrict__ psum, float* __restrict__ pcnt){
  int n = blockIdx.x, t = threadIdx.x;
  int g = batch[n];
  atomicAdd(&psum[g*64+t], bf2f(h3[(size_t)n*64+t]));
  if (t==0) atomicAdd(&pcnt[g], 1.0f);
}

__global__ __launch_bounds__(64) void head_kernel(const float* __restrict__ psum,
        const float* __restrict__ pcnt,
        const float* __restrict__ Wmu, const float* __restrict__ bmu,
        const float* __restrict__ Wlv, const float* __restrict__ blv,
        float* __restrict__ out){
  int g = blockIdx.x, t = threadIdx.x;
  __shared__ float p[64];
  float cnt = fmaxf(pcnt[g], 1.0f);
  p[t] = psum[g*64+t] / cnt;
  __syncthreads();
  float mu = bmu[t], lv = blv[t];
  for (int k=0;k<64;++k){
    float pk = p[k];
    mu = fmaf(pk, Wmu[(size_t)k*64+t], mu);
    lv = fmaf(pk, Wlv[(size_t)k*64+t], lv);
  }
  // eps = jax.random.normal(key(42), (64,64)) with jax_threefry_partitionable=True:
  //   per flat index i (uint64 counter): threefry2x32(key=(0,42), hi32(i), lo32(i)),
  //   32-bit draw = x0' ^ x1'.
  int i = g*64 + t;                       // flat index into (64,64)
  unsigned x0 = 0u, x1 = (unsigned)i;
  threefry2x32(0u, 42u, x0, x1);
  unsigned bits = x0 ^ x1;
  float f = __uint_as_float((bits>>9) | 0x3F800000u) - 1.0f;   // [0,1)
  const float lo = __uint_as_float(0xBF7FFFFFu);               // -(1-2^-24)
  float u = fmaxf(lo, f*2.0f + lo);                            // (hi-lo) rounds to 2.0f
  float eps = 1.41421356f * erfinv_approx(u);
  float z = mu + eps * expf(0.5f*lv);
  out[i]        = mu;
  out[4096 + i] = lv;
  out[8192 + i] = z;
}

// ---------------- launch ----------------
extern "C" void kernel_launch(void* const* d_in, const int* in_sizes, int n_in,
                              void* d_out, int out_size, void* d_ws, size_t ws_size,
                              hipStream_t stream){
  const float* x    = (const float*)d_in[0];
  const int*   ei   = (const int*)d_in[1];
  const int*   batch= (const int*)d_in[2];
  const float* W1   = (const float*)d_in[3];
  const float* a1s  = (const float*)d_in[4];
  const float* a1d  = (const float*)d_in[5];
  const float* b1   = (const float*)d_in[6];
  const float* W2   = (const float*)d_in[7];
  const float* a2s  = (const float*)d_in[8];
  const float* a2d  = (const float*)d_in[9];
  const float* b2   = (const float*)d_in[10];
  const float* W3   = (const float*)d_in[11];
  const float* a3s  = (const float*)d_in[12];
  const float* a3d  = (const float*)d_in[13];
  const float* b3   = (const float*)d_in[14];
  const float* Wmu  = (const float*)d_in[15];
  const float* bmu  = (const float*)d_in[16];
  const float* Wlv  = (const float*)d_in[17];
  const float* blv  = (const float*)d_in[18];
  float* out = (float*)d_out;

  const int N = N_NODES, E = N_EDGES;
  const int ET = E + N;

  char* ws = (char*)d_ws;
  size_t o = 0;
  auto alloc = [&](size_t bytes)->void*{
    void* p = ws + o; o += (bytes + 255) & ~(size_t)255; return p;
  };
  bf16*  hA      = (bf16*) alloc((size_t)N*256*2);   // 25.6 MB
  bf16*  hB      = (bf16*) alloc((size_t)N*256*2);   // 25.6 MB
  float* als     = (float*)alloc((size_t)N*4*4);
  float* ald     = (float*)alloc((size_t)N*4*4);
  int*   deg     = (int*)  alloc((size_t)(N+1)*4);
  int*   off     = (int*)  alloc((size_t)(N+1)*4);
  int*   cursor  = (int*)  alloc((size_t)(N+1)*4);
  int*   csr_src = (int*)  alloc((size_t)ET*4);
  float* psum    = (float*)alloc(64*64*4);
  float* pcnt    = (float*)alloc(64*4);
  (void)ws_size; (void)n_in; (void)in_sizes; (void)out_size;

  const int TB = 256;
  const int egrid = (ET + TB - 1)/TB;

  // CSR by destination (rebuilt every call; ws is re-poisoned each timed launch)
  set_deg_kernel<<<(N+TB-1)/TB, TB, 0, stream>>>(deg, N);
  count_kernel<<<(E+TB-1)/TB, TB, 0, stream>>>(ei, deg, E);
  scan_kernel<<<1, 1024, 0, stream>>>(deg, off, cursor, N);
  fill_kernel<<<egrid, TB, 0, stream>>>(ei, cursor, csr_src, E, N);

  // ---- layer 1: x(f32) @ W1, H=4, ELU ----
  gemm_kernel<256,false><<<N, 64, 0, stream>>>(x, W1, hB);
  attn_coef_kernel<4><<<N, 256, 0, stream>>>(hB, a1s, a1d, als, ald);
  aggregate_kernel<4,true><<<N, 256, 0, stream>>>(hB, als, ald, off, csr_src, b1, hA);

  // ---- layer 2: hA(bf16) @ W2, H=4, ELU ----
  gemm_kernel<256,true><<<N, 64, 0, stream>>>(hA, W2, hB);
  attn_coef_kernel<4><<<N, 256, 0, stream>>>(hB, a2s, a2d, als, ald);
  aggregate_kernel<4,true><<<N, 256, 0, stream>>>(hB, als, ald, off, csr_src, b2, hA);

  // ---- layer 3: hA(bf16) @ W3, H=1, no ELU ----
  gemm_kernel<64,true><<<N, 64, 0, stream>>>(hA, W3, hB);
  attn_coef_kernel<1><<<N, 64, 0, stream>>>(hB, a3s, a3d, als, ald);
  aggregate_kernel<1,false><<<N, 64, 0, stream>>>(hB, als, ald, off, csr_src, b3, hA);

  // ---- pool + VAE head ----
  hipMemsetAsync(psum, 0, 64*64*4, stream);
  hipMemsetAsync(pcnt, 0, 64*4, stream);
  pool_kernel<<<N, 64, 0, stream>>>(hA, batch, psum, pcnt);
  head_kernel<<<64, 64, 0, stream>>>(psum, pcnt, Wmu, bmu, Wlv, blv, out);
}

// Round 5
// 1640.626 us; speedup vs baseline: 1.3842x; 1.3842x over previous
//
#include <hip/hip_runtime.h>
#include <hip/hip_bf16.h>
#include <cstdint>
#include <math.h>

// PathwayGraphEncoder: 3-layer GAT (+self-loops, scatter-softmax) -> mean pool
// -> VAE head with JAX partitionable-threefry eps.
// R5: multi-row GEMM (32 rows/block, x-tile in LDS) — kills the 32x redundant
// W traffic through L1 that made R4's gemm L1-BW-bound (405us, VALUBusy 15%).

#define N_NODES 50000
#define N_EDGES 800000
#define NEG_SLOPE 0.2f

typedef __hip_bfloat16 bf16;

__device__ __forceinline__ float bf2f(bf16 v){ return __bfloat162float(v); }
__device__ __forceinline__ float bflo(unsigned u){ union{unsigned u; float f;} c; c.u = u<<16; return c.f; }
__device__ __forceinline__ float bfhi(unsigned u){ union{unsigned u; float f;} c; c.u = u & 0xFFFF0000u; return c.f; }
__device__ __forceinline__ float leaky(float v){ return v>0.f ? v : NEG_SLOPE*v; }

// ---------------- threefry2x32 (JAX-compatible) ----------------
__device__ __forceinline__ void tf_round(unsigned& x0, unsigned& x1, int r){
  x0 += x1; x1 = (x1<<r)|(x1>>(32-r)); x1 ^= x0;
}
__device__ __forceinline__ void threefry2x32(unsigned k0, unsigned k1, unsigned& x0, unsigned& x1){
  unsigned ks2 = k0 ^ k1 ^ 0x1BD11BDAu;
  x0 += k0; x1 += k1;
  tf_round(x0,x1,13); tf_round(x0,x1,15); tf_round(x0,x1,26); tf_round(x0,x1,6);
  x0 += k1; x1 += ks2 + 1u;
  tf_round(x0,x1,17); tf_round(x0,x1,29); tf_round(x0,x1,16); tf_round(x0,x1,24);
  x0 += ks2; x1 += k0 + 2u;
  tf_round(x0,x1,13); tf_round(x0,x1,15); tf_round(x0,x1,26); tf_round(x0,x1,6);
  x0 += k0; x1 += k1 + 3u;
  tf_round(x0,x1,17); tf_round(x0,x1,29); tf_round(x0,x1,16); tf_round(x0,x1,24);
  x0 += k1; x1 += ks2 + 4u;
  tf_round(x0,x1,13); tf_round(x0,x1,15); tf_round(x0,x1,26); tf_round(x0,x1,6);
  x0 += ks2; x1 += k0 + 5u;
}

// Giles single-precision erfinv (XLA ErfInv32 coefficients)
__device__ __forceinline__ float erfinv_approx(float x){
  float w = -log1pf(-x*x);
  float p;
  if (w < 5.0f){
    w = w - 2.5f;
    p = 2.81022636e-08f;
    p = fmaf(p,w,3.43273939e-07f);
    p = fmaf(p,w,-3.5233877e-06f);
    p = fmaf(p,w,-4.39150654e-06f);
    p = fmaf(p,w,0.00021858087f);
    p = fmaf(p,w,-0.00125372503f);
    p = fmaf(p,w,-0.00417768164f);
    p = fmaf(p,w,0.246640727f);
    p = fmaf(p,w,1.50140941f);
  } else {
    w = sqrtf(w) - 3.0f;
    p = -0.000200214257f;
    p = fmaf(p,w,0.000100950558f);
    p = fmaf(p,w,0.00134934322f);
    p = fmaf(p,w,-0.00367342844f);
    p = fmaf(p,w,0.00573950773f);
    p = fmaf(p,w,-0.0076224613f);
    p = fmaf(p,w,0.00943887047f);
    p = fmaf(p,w,1.00167406f);
    p = fmaf(p,w,2.83297682f);
  }
  return p*x;
}

// ------- multi-row GEMM: out[n,:] = in[n,:] @ W  (IN=256; 32 rows/block) -------
// 256 threads = 4 waves; wave w computes rows w*8..w*8+7.
// OUT=256: each lane 4 consecutive cols (float4 W loads).
// OUT=64 : each lane 1 col (scalar W loads).
template<int OUT, bool INBF>
__global__ __launch_bounds__(256) void gemm_mr_kernel(const void* __restrict__ inp,
        const float* __restrict__ W, bf16* __restrict__ out, int N){
  __shared__ float xs[32][256];     // [row][k], 32 KB
  const int t = threadIdx.x;
  const int n0 = blockIdx.x*32;
  // stage 32 rows of input (coalesced, b128 LDS writes)
  #pragma unroll
  for (int j=0;j<8;++j){
    int row = (t>>6) + 4*j;
    int c4  = (t&63)*4;
    int gr  = n0 + row;
    float4 v = make_float4(0.f,0.f,0.f,0.f);
    if (gr < N){
      if constexpr (INBF){
        uint2 uv = *(const uint2*)((const bf16*)inp + (size_t)gr*256 + c4);
        v.x = bflo(uv.x); v.y = bfhi(uv.x); v.z = bflo(uv.y); v.w = bfhi(uv.y);
      } else {
        v = *(const float4*)((const float*)inp + (size_t)gr*256 + c4);
      }
    }
    *(float4*)&xs[row][c4] = v;
  }
  __syncthreads();
  const int w = t>>6, lane = t&63;

  if constexpr (OUT == 256){
    float acc[8][4] = {};
    const float4* Wp = (const float4*)W;      // [k][64 float4]
    for (int k4=0; k4<64; ++k4){
      float4 wv0 = Wp[(4*k4+0)*64 + lane];
      float4 wv1 = Wp[(4*k4+1)*64 + lane];
      float4 wv2 = Wp[(4*k4+2)*64 + lane];
      float4 wv3 = Wp[(4*k4+3)*64 + lane];
      #pragma unroll
      for (int j=0;j<8;++j){
        float4 xv = *(const float4*)&xs[w*8+j][4*k4];   // b128 broadcast
        acc[j][0] = fmaf(xv.x, wv0.x, acc[j][0]);
        acc[j][1] = fmaf(xv.x, wv0.y, acc[j][1]);
        acc[j][2] = fmaf(xv.x, wv0.z, acc[j][2]);
        acc[j][3] = fmaf(xv.x, wv0.w, acc[j][3]);
        acc[j][0] = fmaf(xv.y, wv1.x, acc[j][0]);
        acc[j][1] = fmaf(xv.y, wv1.y, acc[j][1]);
        acc[j][2] = fmaf(xv.y, wv1.z, acc[j][2]);
        acc[j][3] = fmaf(xv.y, wv1.w, acc[j][3]);
        acc[j][0] = fmaf(xv.z, wv2.x, acc[j][0]);
        acc[j][1] = fmaf(xv.z, wv2.y, acc[j][1]);
        acc[j][2] = fmaf(xv.z, wv2.z, acc[j][2]);
        acc[j][3] = fmaf(xv.z, wv2.w, acc[j][3]);
        acc[j][0] = fmaf(xv.w, wv3.x, acc[j][0]);
        acc[j][1] = fmaf(xv.w, wv3.y, acc[j][1]);
        acc[j][2] = fmaf(xv.w, wv3.z, acc[j][2]);
        acc[j][3] = fmaf(xv.w, wv3.w, acc[j][3]);
      }
    }
    #pragma unroll
    for (int j=0;j<8;++j){
      int gr = n0 + w*8 + j;
      if (gr < N){
        union { bf16 h[4]; uint2 u; } pk;
        pk.h[0]=__float2bfloat16(acc[j][0]); pk.h[1]=__float2bfloat16(acc[j][1]);
        pk.h[2]=__float2bfloat16(acc[j][2]); pk.h[3]=__float2bfloat16(acc[j][3]);
        *(uint2*)(out + (size_t)gr*256 + lane*4) = pk.u;
      }
    }
  } else {  // OUT == 64
    float acc[8] = {};
    for (int k4=0; k4<64; ++k4){
      float wv0 = W[(4*k4+0)*64 + lane];
      float wv1 = W[(4*k4+1)*64 + lane];
      float wv2 = W[(4*k4+2)*64 + lane];
      float wv3 = W[(4*k4+3)*64 + lane];
      #pragma unroll
      for (int j=0;j<8;++j){
        float4 xv = *(const float4*)&xs[w*8+j][4*k4];
        acc[j] = fmaf(xv.x, wv0, acc[j]);
        acc[j] = fmaf(xv.y, wv1, acc[j]);
        acc[j] = fmaf(xv.z, wv2, acc[j]);
        acc[j] = fmaf(xv.w, wv3, acc[j]);
      }
    }
    #pragma unroll
    for (int j=0;j<8;++j){
      int gr = n0 + w*8 + j;
      if (gr < N) out[(size_t)gr*64 + lane] = __float2bfloat16(acc[j]);
    }
  }
}

// ---------------- attention coefficients: als/ald [N,H] ----------------
template<int H>
__global__ __launch_bounds__(H*64) void attn_coef_kernel(const bf16* __restrict__ h,
        const float* __restrict__ a_s, const float* __restrict__ a_d,
        float* __restrict__ als, float* __restrict__ ald){
  const int n = blockIdx.x, t = threadIdx.x;
  float hv = bf2f(h[(size_t)n*(H*64) + t]);
  float ps = hv * a_s[t];
  float pd = hv * a_d[t];
  #pragma unroll
  for (int o=32;o>0;o>>=1){ ps += __shfl_xor(ps,o); pd += __shfl_xor(pd,o); }
  if ((t & 63)==0){ int head = t>>6; als[n*H+head]=ps; ald[n*H+head]=pd; }
}

// ---------------- CSR build (by destination, includes self-loops) ----------------
__global__ void set_deg_kernel(int* deg, int N){
  int i = blockIdx.x*blockDim.x+threadIdx.x; if (i<N) deg[i]=1;   // self loop
}
__global__ void count_kernel(const int* __restrict__ ei, int* __restrict__ deg, int E){
  int e = blockIdx.x*blockDim.x+threadIdx.x; if (e<E) atomicAdd(&deg[ei[E+e]], 1);
}
__global__ __launch_bounds__(1024) void scan_kernel(const int* __restrict__ deg,
        int* __restrict__ off, int* __restrict__ cursor, int N){
  __shared__ int sh[1024];
  __shared__ int carry_s;
  int t = threadIdx.x;
  if (t==0) carry_s = 0;
  __syncthreads();
  for (int base=0; base<N; base+=1024){
    int v = (base+t < N)? deg[base+t] : 0;
    sh[t]=v; __syncthreads();
    for (int o=1;o<1024;o<<=1){
      int add = (t>=o)? sh[t-o] : 0;
      __syncthreads();
      sh[t] += add;
      __syncthreads();
    }
    int incl = sh[t];
    int excl = incl - v;
    int carry = carry_s;
    if (base+t < N){ off[base+t]=carry+excl; cursor[base+t]=carry+excl; }
    __syncthreads();
    if (t==1023) carry_s = carry + incl;
    __syncthreads();
  }
  if (t==0) off[N] = carry_s;
}
__global__ void fill_kernel(const int* __restrict__ ei, int* __restrict__ cursor,
        int* __restrict__ csr_src, int E, int N){
  int e = blockIdx.x*blockDim.x+threadIdx.x;
  if (e >= E+N) return;
  int s_ = (e < E) ? ei[e]   : e-E;
  int d_ = (e < E) ? ei[E+e] : e-E;
  int p = atomicAdd(&cursor[d_], 1);
  csr_src[p] = s_;
}

// ------- fused scatter-softmax + aggregate: out[n,:] = sum alpha*h[src,:] + b -------
template<int H, bool ELU>
__global__ __launch_bounds__(H*64) void aggregate_kernel(const bf16* __restrict__ h,
        const float* __restrict__ als, const float* __restrict__ ald,
        const int* __restrict__ off, const int* __restrict__ csr_src,
        const float* __restrict__ bias, bf16* __restrict__ out){
  const int n = blockIdx.x, t = threadIdx.x, head = t>>6;
  const int D = H*64;
  const int p0 = off[n], p1 = off[n+1];
  const float aldn = ald[n*H + head];
  float m = -1e30f;
  for (int p=p0; p<p1; ++p){
    float e = leaky(als[csr_src[p]*H + head] + aldn);
    m = fmaxf(m, e);
  }
  float s = 0.f, acc = 0.f;
  for (int p=p0; p<p1; ++p){
    int src = csr_src[p];
    float e = leaky(als[src*H + head] + aldn);
    float w = expf(e - m);
    s += w;
    acc = fmaf(bf2f(h[(size_t)src*D + t]), w, acc);
  }
  float r = acc/(s + 1e-16f) + bias[t];
  if (ELU) r = (r > 0.f) ? r : expm1f(r);
  out[(size_t)n*D + t] = __float2bfloat16(r);
}

// ---------------- pooling + VAE head ----------------
__global__ __launch_bounds__(64) void pool_kernel(const bf16* __restrict__ h3,
        const int* __restrict__ batch, float* __restrict__ psum, float* __restrict__ pcnt){
  int n = blockIdx.x, t = threadIdx.x;
  int g = batch[n];
  atomicAdd(&psum[g*64+t], bf2f(h3[(size_t)n*64+t]));
  if (t==0) atomicAdd(&pcnt[g], 1.0f);
}

__global__ __launch_bounds__(64) void head_kernel(const float* __restrict__ psum,
        const float* __restrict__ pcnt,
        const float* __restrict__ Wmu, const float* __restrict__ bmu,
        const float* __restrict__ Wlv, const float* __restrict__ blv,
        float* __restrict__ out){
  int g = blockIdx.x, t = threadIdx.x;
  __shared__ float p[64];
  float cnt = fmaxf(pcnt[g], 1.0f);
  p[t] = psum[g*64+t] / cnt;
  __syncthreads();
  float mu = bmu[t], lv = blv[t];
  for (int k=0;k<64;++k){
    float pk = p[k];
    mu = fmaf(pk, Wmu[(size_t)k*64+t], mu);
    lv = fmaf(pk, Wlv[(size_t)k*64+t], lv);
  }
  // eps = jax.random.normal(key(42), (64,64)), jax_threefry_partitionable:
  //   per flat i: threefry2x32(key=(0,42), hi32(i)=0, lo32(i)=i), bits = x0'^x1'.
  int i = g*64 + t;
  unsigned x0 = 0u, x1 = (unsigned)i;
  threefry2x32(0u, 42u, x0, x1);
  unsigned bits = x0 ^ x1;
  float f = __uint_as_float((bits>>9) | 0x3F800000u) - 1.0f;   // [0,1)
  const float lo = __uint_as_float(0xBF7FFFFFu);               // -(1-2^-24)
  float u = fmaxf(lo, f*2.0f + lo);
  float eps = 1.41421356f * erfinv_approx(u);
  float z = mu + eps * expf(0.5f*lv);
  out[i]        = mu;
  out[4096 + i] = lv;
  out[8192 + i] = z;
}

// ---------------- launch ----------------
extern "C" void kernel_launch(void* const* d_in, const int* in_sizes, int n_in,
                              void* d_out, int out_size, void* d_ws, size_t ws_size,
                              hipStream_t stream){
  const float* x    = (const float*)d_in[0];
  const int*   ei   = (const int*)d_in[1];
  const int*   batch= (const int*)d_in[2];
  const float* W1   = (const float*)d_in[3];
  const float* a1s  = (const float*)d_in[4];
  const float* a1d  = (const float*)d_in[5];
  const float* b1   = (const float*)d_in[6];
  const float* W2   = (const float*)d_in[7];
  const float* a2s  = (const float*)d_in[8];
  const float* a2d  = (const float*)d_in[9];
  const float* b2   = (const float*)d_in[10];
  const float* W3   = (const float*)d_in[11];
  const float* a3s  = (const float*)d_in[12];
  const float* a3d  = (const float*)d_in[13];
  const float* b3   = (const float*)d_in[14];
  const float* Wmu  = (const float*)d_in[15];
  const float* bmu  = (const float*)d_in[16];
  const float* Wlv  = (const float*)d_in[17];
  const float* blv  = (const float*)d_in[18];
  float* out = (float*)d_out;

  const int N = N_NODES, E = N_EDGES;
  const int ET = E + N;

  char* ws = (char*)d_ws;
  size_t o = 0;
  auto alloc = [&](size_t bytes)->void*{
    void* p = ws + o; o += (bytes + 255) & ~(size_t)255; return p;
  };
  bf16*  hA      = (bf16*) alloc((size_t)N*256*2);   // 25.6 MB
  bf16*  hB      = (bf16*) alloc((size_t)N*256*2);   // 25.6 MB
  float* als     = (float*)alloc((size_t)N*4*4);
  float* ald     = (float*)alloc((size_t)N*4*4);
  int*   deg     = (int*)  alloc((size_t)(N+1)*4);
  int*   off     = (int*)  alloc((size_t)(N+1)*4);
  int*   cursor  = (int*)  alloc((size_t)(N+1)*4);
  int*   csr_src = (int*)  alloc((size_t)ET*4);
  float* psum    = (float*)alloc(64*64*4);
  float* pcnt    = (float*)alloc(64*4);
  (void)ws_size; (void)n_in; (void)in_sizes; (void)out_size;

  const int TB = 256;
  const int egrid = (ET + TB - 1)/TB;
  const int ggrid = (N + 31)/32;

  // CSR by destination (rebuilt every call; ws is re-poisoned each timed launch)
  set_deg_kernel<<<(N+TB-1)/TB, TB, 0, stream>>>(deg, N);
  count_kernel<<<(E+TB-1)/TB, TB, 0, stream>>>(ei, deg, E);
  scan_kernel<<<1, 1024, 0, stream>>>(deg, off, cursor, N);
  fill_kernel<<<egrid, TB, 0, stream>>>(ei, cursor, csr_src, E, N);

  // ---- layer 1: x(f32) @ W1, H=4, ELU ----
  gemm_mr_kernel<256,false><<<ggrid, 256, 0, stream>>>(x, W1, hB, N);
  attn_coef_kernel<4><<<N, 256, 0, stream>>>(hB, a1s, a1d, als, ald);
  aggregate_kernel<4,true><<<N, 256, 0, stream>>>(hB, als, ald, off, csr_src, b1, hA);

  // ---- layer 2: hA(bf16) @ W2, H=4, ELU ----
  gemm_mr_kernel<256,true><<<ggrid, 256, 0, stream>>>(hA, W2, hB, N);
  attn_coef_kernel<4><<<N, 256, 0, stream>>>(hB, a2s, a2d, als, ald);
  aggregate_kernel<4,true><<<N, 256, 0, stream>>>(hB, als, ald, off, csr_src, b2, hA);

  // ---- layer 3: hA(bf16) @ W3, H=1, no ELU ----
  gemm_mr_kernel<64,true><<<ggrid, 256, 0, stream>>>(hA, W3, hB, N);
  attn_coef_kernel<1><<<N, 64, 0, stream>>>(hB, a3s, a3d, als, ald);
  aggregate_kernel<1,false><<<N, 64, 0, stream>>>(hB, als, ald, off, csr_src, b3, hA);

  // ---- pool + VAE head ----
  hipMemsetAsync(psum, 0, 64*64*4, stream);
  hipMemsetAsync(pcnt, 0, 64*4, stream);
  pool_kernel<<<N, 64, 0, stream>>>(hA, batch, psum, pcnt);
  head_kernel<<<64, 64, 0, stream>>>(psum, pcnt, Wmu, bmu, Wlv, blv, out);
}

// Round 6
// 758.969 us; speedup vs baseline: 2.9922x; 2.1616x over previous
//
#include <hip/hip_runtime.h>
#include <hip/hip_bf16.h>
#include <cstdint>
#include <math.h>

// PathwayGraphEncoder: 3-layer GAT (+self-loops, scatter-softmax) -> mean pool
// -> VAE head with JAX partitionable-threefry eps.
// R6: (1) chunked pool (kills 3.2M-atomic serialization, was 388us),
//     (2) scan-free CSR (unordered segment starts via atomicAdd),
//     (3) 1-wave-per-node aggregate with uint2 (4xbf16) gathers,
//     (4) attn coefficients fused into GEMM epilogue (segmented shfl reduce).

#define N_NODES 50000
#define N_EDGES 800000
#define NEG_SLOPE 0.2f

typedef __hip_bfloat16 bf16;

__device__ __forceinline__ float bf2f(bf16 v){ return __bfloat162float(v); }
__device__ __forceinline__ float bflo(unsigned u){ union{unsigned u; float f;} c; c.u = u<<16; return c.f; }
__device__ __forceinline__ float bfhi(unsigned u){ union{unsigned u; float f;} c; c.u = u & 0xFFFF0000u; return c.f; }
__device__ __forceinline__ float leaky(float v){ return v>0.f ? v : NEG_SLOPE*v; }

// ---------------- threefry2x32 (JAX-compatible) ----------------
__device__ __forceinline__ void tf_round(unsigned& x0, unsigned& x1, int r){
  x0 += x1; x1 = (x1<<r)|(x1>>(32-r)); x1 ^= x0;
}
__device__ __forceinline__ void threefry2x32(unsigned k0, unsigned k1, unsigned& x0, unsigned& x1){
  unsigned ks2 = k0 ^ k1 ^ 0x1BD11BDAu;
  x0 += k0; x1 += k1;
  tf_round(x0,x1,13); tf_round(x0,x1,15); tf_round(x0,x1,26); tf_round(x0,x1,6);
  x0 += k1; x1 += ks2 + 1u;
  tf_round(x0,x1,17); tf_round(x0,x1,29); tf_round(x0,x1,16); tf_round(x0,x1,24);
  x0 += ks2; x1 += k0 + 2u;
  tf_round(x0,x1,13); tf_round(x0,x1,15); tf_round(x0,x1,26); tf_round(x0,x1,6);
  x0 += k0; x1 += k1 + 3u;
  tf_round(x0,x1,17); tf_round(x0,x1,29); tf_round(x0,x1,16); tf_round(x0,x1,24);
  x0 += k1; x1 += ks2 + 4u;
  tf_round(x0,x1,13); tf_round(x0,x1,15); tf_round(x0,x1,26); tf_round(x0,x1,6);
  x0 += ks2; x1 += k0 + 5u;
}

// Giles single-precision erfinv (XLA ErfInv32 coefficients)
__device__ __forceinline__ float erfinv_approx(float x){
  float w = -log1pf(-x*x);
  float p;
  if (w < 5.0f){
    w = w - 2.5f;
    p = 2.81022636e-08f;
    p = fmaf(p,w,3.43273939e-07f);
    p = fmaf(p,w,-3.5233877e-06f);
    p = fmaf(p,w,-4.39150654e-06f);
    p = fmaf(p,w,0.00021858087f);
    p = fmaf(p,w,-0.00125372503f);
    p = fmaf(p,w,-0.00417768164f);
    p = fmaf(p,w,0.246640727f);
    p = fmaf(p,w,1.50140941f);
  } else {
    w = sqrtf(w) - 3.0f;
    p = -0.000200214257f;
    p = fmaf(p,w,0.000100950558f);
    p = fmaf(p,w,0.00134934322f);
    p = fmaf(p,w,-0.00367342844f);
    p = fmaf(p,w,0.00573950773f);
    p = fmaf(p,w,-0.0076224613f);
    p = fmaf(p,w,0.00943887047f);
    p = fmaf(p,w,1.00167406f);
    p = fmaf(p,w,2.83297682f);
  }
  return p*x;
}

// ------- multi-row GEMM + fused attention coefficients -------
// 32 rows/block, 256 threads = 4 waves; wave w computes rows w*8..w*8+7.
// OUT=256 (H=4): lane owns 4 consecutive cols; head h = lane>>4.
// OUT=64  (H=1): lane owns 1 col.
template<int OUT, bool INBF>
__global__ __launch_bounds__(256) void gemm_mr_kernel(const void* __restrict__ inp,
        const float* __restrict__ W, bf16* __restrict__ out,
        const float* __restrict__ a_s, const float* __restrict__ a_d,
        float* __restrict__ als, float* __restrict__ ald, int N){
  __shared__ float xs[32][256];     // [row][k], 32 KB
  const int t = threadIdx.x;
  const int n0 = blockIdx.x*32;
  #pragma unroll
  for (int j=0;j<8;++j){
    int row = (t>>6) + 4*j;
    int c4  = (t&63)*4;
    int gr  = n0 + row;
    float4 v = make_float4(0.f,0.f,0.f,0.f);
    if (gr < N){
      if constexpr (INBF){
        uint2 uv = *(const uint2*)((const bf16*)inp + (size_t)gr*256 + c4);
        v.x = bflo(uv.x); v.y = bfhi(uv.x); v.z = bflo(uv.y); v.w = bfhi(uv.y);
      } else {
        v = *(const float4*)((const float*)inp + (size_t)gr*256 + c4);
      }
    }
    *(float4*)&xs[row][c4] = v;
  }
  __syncthreads();
  const int w = t>>6, lane = t&63;

  if constexpr (OUT == 256){
    float acc[8][4] = {};
    const float4* Wp = (const float4*)W;      // [k][64 float4]
    for (int k4=0; k4<64; ++k4){
      float4 wv0 = Wp[(4*k4+0)*64 + lane];
      float4 wv1 = Wp[(4*k4+1)*64 + lane];
      float4 wv2 = Wp[(4*k4+2)*64 + lane];
      float4 wv3 = Wp[(4*k4+3)*64 + lane];
      #pragma unroll
      for (int j=0;j<8;++j){
        float4 xv = *(const float4*)&xs[w*8+j][4*k4];   // broadcast
        acc[j][0] = fmaf(xv.x, wv0.x, acc[j][0]);
        acc[j][1] = fmaf(xv.x, wv0.y, acc[j][1]);
        acc[j][2] = fmaf(xv.x, wv0.z, acc[j][2]);
        acc[j][3] = fmaf(xv.x, wv0.w, acc[j][3]);
        acc[j][0] = fmaf(xv.y, wv1.x, acc[j][0]);
        acc[j][1] = fmaf(xv.y, wv1.y, acc[j][1]);
        acc[j][2] = fmaf(xv.y, wv1.z, acc[j][2]);
        acc[j][3] = fmaf(xv.y, wv1.w, acc[j][3]);
        acc[j][0] = fmaf(xv.z, wv2.x, acc[j][0]);
        acc[j][1] = fmaf(xv.z, wv2.y, acc[j][1]);
        acc[j][2] = fmaf(xv.z, wv2.z, acc[j][2]);
        acc[j][3] = fmaf(xv.z, wv2.w, acc[j][3]);
        acc[j][0] = fmaf(xv.w, wv3.x, acc[j][0]);
        acc[j][1] = fmaf(xv.w, wv3.y, acc[j][1]);
        acc[j][2] = fmaf(xv.w, wv3.z, acc[j][2]);
        acc[j][3] = fmaf(xv.w, wv3.w, acc[j][3]);
      }
    }
    const float4 asv = *(const float4*)(a_s + 4*lane);
    const float4 adv = *(const float4*)(a_d + 4*lane);
    #pragma unroll
    for (int j=0;j<8;++j){
      int gr = n0 + w*8 + j;
      if (gr >= N) continue;
      union { bf16 h[4]; uint2 u; } pk;
      pk.h[0]=__float2bfloat16(acc[j][0]); pk.h[1]=__float2bfloat16(acc[j][1]);
      pk.h[2]=__float2bfloat16(acc[j][2]); pk.h[3]=__float2bfloat16(acc[j][3]);
      *(uint2*)(out + (size_t)gr*256 + lane*4) = pk.u;
      float ps = acc[j][0]*asv.x + acc[j][1]*asv.y + acc[j][2]*asv.z + acc[j][3]*asv.w;
      float pd = acc[j][0]*adv.x + acc[j][1]*adv.y + acc[j][2]*adv.z + acc[j][3]*adv.w;
      #pragma unroll
      for (int o=1;o<16;o<<=1){ ps += __shfl_xor(ps,o); pd += __shfl_xor(pd,o); }
      if ((lane&15)==0){
        int head = lane>>4;
        als[gr*4+head] = ps; ald[gr*4+head] = pd;
      }
    }
  } else {  // OUT == 64, H=1
    float acc[8] = {};
    for (int k4=0; k4<64; ++k4){
      float wv0 = W[(4*k4+0)*64 + lane];
      float wv1 = W[(4*k4+1)*64 + lane];
      float wv2 = W[(4*k4+2)*64 + lane];
      float wv3 = W[(4*k4+3)*64 + lane];
      #pragma unroll
      for (int j=0;j<8;++j){
        float4 xv = *(const float4*)&xs[w*8+j][4*k4];
        acc[j] = fmaf(xv.x, wv0, acc[j]);
        acc[j] = fmaf(xv.y, wv1, acc[j]);
        acc[j] = fmaf(xv.z, wv2, acc[j]);
        acc[j] = fmaf(xv.w, wv3, acc[j]);
      }
    }
    float as1 = a_s[lane], ad1 = a_d[lane];
    #pragma unroll
    for (int j=0;j<8;++j){
      int gr = n0 + w*8 + j;
      if (gr >= N) continue;
      out[(size_t)gr*64 + lane] = __float2bfloat16(acc[j]);
      float ps = acc[j]*as1, pd = acc[j]*ad1;
      #pragma unroll
      for (int o=1;o<64;o<<=1){ ps += __shfl_xor(ps,o); pd += __shfl_xor(pd,o); }
      if (lane==0){ als[gr] = ps; ald[gr] = pd; }
    }
  }
}

// ---------------- scan-free CSR build (by destination, + self-loops) ----------------
__global__ void count_kernel(const int* __restrict__ ei, int* __restrict__ deg, int E){
  int e = blockIdx.x*blockDim.x+threadIdx.x; if (e<E) atomicAdd(&deg[ei[E+e]], 1);
}
__global__ void assign_kernel(const int* __restrict__ deg, int* __restrict__ off,
        int* __restrict__ cursor, int* __restrict__ total, int N){
  int i = blockIdx.x*blockDim.x+threadIdx.x;
  if (i<N){
    int d = deg[i] + 1;                       // +1 self-loop
    int start = atomicAdd(total, d);          // unordered segments: fine
    off[i] = start; cursor[i] = start;
  }
}
__global__ void fill_kernel(const int* __restrict__ ei, int* __restrict__ cursor,
        int* __restrict__ csr_src, int E, int N){
  int e = blockIdx.x*blockDim.x+threadIdx.x;
  if (e >= E+N) return;
  int s_ = (e < E) ? ei[e]   : e-E;
  int d_ = (e < E) ? ei[E+e] : e-E;
  int p = atomicAdd(&cursor[d_], 1);
  csr_src[p] = s_;
}

// ------- fused scatter-softmax + aggregate: 1 wave per node, uint2 gathers -------
template<int H, bool ELU>
__global__ __launch_bounds__(64) void aggregate_kernel(const bf16* __restrict__ h,
        const float* __restrict__ als, const float* __restrict__ ald,
        const int* __restrict__ off, const int* __restrict__ deg,
        const int* __restrict__ csr_src,
        const float* __restrict__ bias, bf16* __restrict__ out){
  const int n = blockIdx.x, lane = threadIdx.x;
  const int D = H*64;
  const int head = (H==4) ? (lane>>4) : 0;
  const int p0 = off[n], p1 = p0 + deg[n] + 1;
  const float aldn = ald[n*H + head];
  float m = -1e30f;
  for (int p=p0; p<p1; ++p){
    float e = leaky(als[csr_src[p]*H + head] + aldn);
    m = fmaxf(m, e);
  }
  if constexpr (H==4){
    float s = 0.f, a0=0.f,a1=0.f,a2=0.f,a3=0.f;
    for (int p=p0; p<p1; ++p){
      int src = csr_src[p];
      float e = leaky(als[src*4 + head] + aldn);
      float wgt = expf(e - m);
      s += wgt;
      uint2 hv = *(const uint2*)(h + (size_t)src*256 + 4*lane);
      a0 = fmaf(bflo(hv.x), wgt, a0);
      a1 = fmaf(bfhi(hv.x), wgt, a1);
      a2 = fmaf(bflo(hv.y), wgt, a2);
      a3 = fmaf(bfhi(hv.y), wgt, a3);
    }
    float inv = 1.f/(s + 1e-16f);
    float r0 = a0*inv + bias[4*lane+0];
    float r1 = a1*inv + bias[4*lane+1];
    float r2 = a2*inv + bias[4*lane+2];
    float r3 = a3*inv + bias[4*lane+3];
    if (ELU){
      r0 = (r0>0.f)?r0:expm1f(r0); r1 = (r1>0.f)?r1:expm1f(r1);
      r2 = (r2>0.f)?r2:expm1f(r2); r3 = (r3>0.f)?r3:expm1f(r3);
    }
    union { bf16 h4[4]; uint2 u; } pk;
    pk.h4[0]=__float2bfloat16(r0); pk.h4[1]=__float2bfloat16(r1);
    pk.h4[2]=__float2bfloat16(r2); pk.h4[3]=__float2bfloat16(r3);
    *(uint2*)(out + (size_t)n*256 + 4*lane) = pk.u;
  } else {
    float s = 0.f, acc = 0.f;
    for (int p=p0; p<p1; ++p){
      int src = csr_src[p];
      float e = leaky(als[src] + aldn);
      float wgt = expf(e - m);
      s += wgt;
      acc = fmaf(bf2f(h[(size_t)src*64 + lane]), wgt, acc);
    }
    float r = acc/(s + 1e-16f) + bias[lane];
    if (ELU) r = (r>0.f)?r:expm1f(r);
    out[(size_t)n*64 + lane] = __float2bfloat16(r);
  }
}

// ---------------- chunked pooling (batch sorted) ----------------
__global__ __launch_bounds__(64) void pool_kernel(const bf16* __restrict__ h3,
        const int* __restrict__ batch, float* __restrict__ psum, float* __restrict__ pcnt,
        int N, int chunk){
  int n0 = blockIdx.x*chunk;
  if (n0 >= N) return;
  int n1 = min(N, n0+chunk);
  int t = threadIdx.x;
  int gcur = batch[n0];
  float acc = 0.f, cnt = 0.f;
  for (int n=n0; n<n1; ++n){
    int g = batch[n];
    if (g != gcur){
      atomicAdd(&psum[gcur*64+t], acc);
      if (t==0) atomicAdd(&pcnt[gcur], cnt);
      acc = 0.f; cnt = 0.f; gcur = g;
    }
    acc += bf2f(h3[(size_t)n*64+t]);
    cnt += 1.f;
  }
  atomicAdd(&psum[gcur*64+t], acc);
  if (t==0) atomicAdd(&pcnt[gcur], cnt);
}

__global__ __launch_bounds__(64) void head_kernel(const float* __restrict__ psum,
        const float* __restrict__ pcnt,
        const float* __restrict__ Wmu, const float* __restrict__ bmu,
        const float* __restrict__ Wlv, const float* __restrict__ blv,
        float* __restrict__ out){
  int g = blockIdx.x, t = threadIdx.x;
  __shared__ float p[64];
  float cnt = fmaxf(pcnt[g], 1.0f);
  p[t] = psum[g*64+t] / cnt;
  __syncthreads();
  float mu = bmu[t], lv = blv[t];
  for (int k=0;k<64;++k){
    float pk = p[k];
    mu = fmaf(pk, Wmu[(size_t)k*64+t], mu);
    lv = fmaf(pk, Wlv[(size_t)k*64+t], lv);
  }
  // eps = jax.random.normal(key(42), (64,64)), jax_threefry_partitionable:
  //   per flat i: threefry2x32(key=(0,42), hi32(i)=0, lo32(i)=i), bits = x0'^x1'.
  int i = g*64 + t;
  unsigned x0 = 0u, x1 = (unsigned)i;
  threefry2x32(0u, 42u, x0, x1);
  unsigned bits = x0 ^ x1;
  float f = __uint_as_float((bits>>9) | 0x3F800000u) - 1.0f;   // [0,1)
  const float lo = __uint_as_float(0xBF7FFFFFu);               // -(1-2^-24)
  float u = fmaxf(lo, f*2.0f + lo);
  float eps = 1.41421356f * erfinv_approx(u);
  float z = mu + eps * expf(0.5f*lv);
  out[i]        = mu;
  out[4096 + i] = lv;
  out[8192 + i] = z;
}

// ---------------- launch ----------------
extern "C" void kernel_launch(void* const* d_in, const int* in_sizes, int n_in,
                              void* d_out, int out_size, void* d_ws, size_t ws_size,
                              hipStream_t stream){
  const float* x    = (const float*)d_in[0];
  const int*   ei   = (const int*)d_in[1];
  const int*   batch= (const int*)d_in[2];
  const float* W1   = (const float*)d_in[3];
  const float* a1s  = (const float*)d_in[4];
  const float* a1d  = (const float*)d_in[5];
  const float* b1   = (const float*)d_in[6];
  const float* W2   = (const float*)d_in[7];
  const float* a2s  = (const float*)d_in[8];
  const float* a2d  = (const float*)d_in[9];
  const float* b2   = (const float*)d_in[10];
  const float* W3   = (const float*)d_in[11];
  const float* a3s  = (const float*)d_in[12];
  const float* a3d  = (const float*)d_in[13];
  const float* b3   = (const float*)d_in[14];
  const float* Wmu  = (const float*)d_in[15];
  const float* bmu  = (const float*)d_in[16];
  const float* Wlv  = (const float*)d_in[17];
  const float* blv  = (const float*)d_in[18];
  float* out = (float*)d_out;

  const int N = N_NODES, E = N_EDGES;
  const int ET = E + N;

  char* ws = (char*)d_ws;
  size_t o = 0;
  auto alloc = [&](size_t bytes)->void*{
    void* p = ws + o; o += (bytes + 255) & ~(size_t)255; return p;
  };
  bf16*  hA      = (bf16*) alloc((size_t)N*256*2);   // 25.6 MB
  bf16*  hB      = (bf16*) alloc((size_t)N*256*2);   // 25.6 MB
  float* als     = (float*)alloc((size_t)N*4*4);
  float* ald     = (float*)alloc((size_t)N*4*4);
  int*   deg     = (int*)  alloc((size_t)N*4);
  int*   off     = (int*)  alloc((size_t)N*4);
  int*   cursor  = (int*)  alloc((size_t)N*4);
  int*   total   = (int*)  alloc(4);
  int*   csr_src = (int*)  alloc((size_t)ET*4);
  float* psum    = (float*)alloc(64*64*4);
  float* pcnt    = (float*)alloc(64*4);
  (void)ws_size; (void)n_in; (void)in_sizes; (void)out_size;

  const int TB = 256;
  const int egrid = (ET + TB - 1)/TB;
  const int ggrid = (N + 31)/32;

  // scan-free CSR by destination (rebuilt every call; ws re-poisoned per launch)
  hipMemsetAsync(deg, 0, (size_t)N*4, stream);
  hipMemsetAsync(total, 0, 4, stream);
  count_kernel<<<(E+TB-1)/TB, TB, 0, stream>>>(ei, deg, E);
  assign_kernel<<<(N+TB-1)/TB, TB, 0, stream>>>(deg, off, cursor, total, N);
  fill_kernel<<<egrid, TB, 0, stream>>>(ei, cursor, csr_src, E, N);

  // ---- layer 1: x(f32) @ W1, H=4, ELU ----
  gemm_mr_kernel<256,false><<<ggrid, 256, 0, stream>>>(x, W1, hB, a1s, a1d, als, ald, N);
  aggregate_kernel<4,true><<<N, 64, 0, stream>>>(hB, als, ald, off, deg, csr_src, b1, hA);

  // ---- layer 2: hA(bf16) @ W2, H=4, ELU ----
  gemm_mr_kernel<256,true><<<ggrid, 256, 0, stream>>>(hA, W2, hB, a2s, a2d, als, ald, N);
  aggregate_kernel<4,true><<<N, 64, 0, stream>>>(hB, als, ald, off, deg, csr_src, b2, hA);

  // ---- layer 3: hA(bf16) @ W3, H=1, no ELU ----
  gemm_mr_kernel<64,true><<<ggrid, 256, 0, stream>>>(hA, W3, hB, a3s, a3d, als, ald, N);
  aggregate_kernel<1,false><<<N, 64, 0, stream>>>(hB, als, ald, off, deg, csr_src, b3, hA);

  // ---- pool + VAE head ----
  hipMemsetAsync(psum, 0, 64*64*4, stream);
  hipMemsetAsync(pcnt, 0, 64*4, stream);
  const int PBLK = 512;
  const int chunk = (N + PBLK - 1)/PBLK;
  pool_kernel<<<PBLK, 64, 0, stream>>>(hA, batch, psum, pcnt, N, chunk);
  head_kernel<<<64, 64, 0, stream>>>(psum, pcnt, Wmu, bmu, Wlv, blv, out);
}

// Round 7
// 624.819 us; speedup vs baseline: 3.6346x; 1.2147x over previous
//
#include <hip/hip_runtime.h>
#include <hip/hip_bf16.h>
#include <cstdint>
#include <math.h>

// PathwayGraphEncoder: 3-layer GAT (+self-loops, scatter-softmax) -> mean pool
// -> VAE head with JAX partitionable-threefry eps.
// R7: MFMA GEMM (16x16x32 bf16). R6's scalar-FMA gemm was 2.5x over the vector
// floor (105us, VALUBusy 56%); matmul belongs on the matrix pipe. W transposed
// to [n][k] bf16 per call; A staged f32->bf16 inline; als/ald fused in epilogue.

#define N_NODES 50000
#define N_EDGES 800000
#define NEG_SLOPE 0.2f

typedef __hip_bfloat16 bf16;
typedef short short8 __attribute__((ext_vector_type(8)));
typedef float floatx4 __attribute__((ext_vector_type(4)));

__device__ __forceinline__ float bf2f(bf16 v){ return __bfloat162float(v); }
__device__ __forceinline__ float bflo(unsigned u){ union{unsigned u; float f;} c; c.u = u<<16; return c.f; }
__device__ __forceinline__ float bfhi(unsigned u){ union{unsigned u; float f;} c; c.u = u & 0xFFFF0000u; return c.f; }
__device__ __forceinline__ float leaky(float v){ return v>0.f ? v : NEG_SLOPE*v; }
__device__ __forceinline__ unsigned short f2bu(float f){
  union{ bf16 b; unsigned short u; } c; c.b = __float2bfloat16(f); return c.u;
}

// ---------------- threefry2x32 (JAX-compatible) ----------------
__device__ __forceinline__ void tf_round(unsigned& x0, unsigned& x1, int r){
  x0 += x1; x1 = (x1<<r)|(x1>>(32-r)); x1 ^= x0;
}
__device__ __forceinline__ void threefry2x32(unsigned k0, unsigned k1, unsigned& x0, unsigned& x1){
  unsigned ks2 = k0 ^ k1 ^ 0x1BD11BDAu;
  x0 += k0; x1 += k1;
  tf_round(x0,x1,13); tf_round(x0,x1,15); tf_round(x0,x1,26); tf_round(x0,x1,6);
  x0 += k1; x1 += ks2 + 1u;
  tf_round(x0,x1,17); tf_round(x0,x1,29); tf_round(x0,x1,16); tf_round(x0,x1,24);
  x0 += ks2; x1 += k0 + 2u;
  tf_round(x0,x1,13); tf_round(x0,x1,15); tf_round(x0,x1,26); tf_round(x0,x1,6);
  x0 += k0; x1 += k1 + 3u;
  tf_round(x0,x1,17); tf_round(x0,x1,29); tf_round(x0,x1,16); tf_round(x0,x1,24);
  x0 += k1; x1 += ks2 + 4u;
  tf_round(x0,x1,13); tf_round(x0,x1,15); tf_round(x0,x1,26); tf_round(x0,x1,6);
  x0 += ks2; x1 += k0 + 5u;
}

// Giles single-precision erfinv (XLA ErfInv32 coefficients)
__device__ __forceinline__ float erfinv_approx(float x){
  float w = -log1pf(-x*x);
  float p;
  if (w < 5.0f){
    w = w - 2.5f;
    p = 2.81022636e-08f;
    p = fmaf(p,w,3.43273939e-07f);
    p = fmaf(p,w,-3.5233877e-06f);
    p = fmaf(p,w,-4.39150654e-06f);
    p = fmaf(p,w,0.00021858087f);
    p = fmaf(p,w,-0.00125372503f);
    p = fmaf(p,w,-0.00417768164f);
    p = fmaf(p,w,0.246640727f);
    p = fmaf(p,w,1.50140941f);
  } else {
    w = sqrtf(w) - 3.0f;
    p = -0.000200214257f;
    p = fmaf(p,w,0.000100950558f);
    p = fmaf(p,w,0.00134934322f);
    p = fmaf(p,w,-0.00367342844f);
    p = fmaf(p,w,0.00573950773f);
    p = fmaf(p,w,-0.0076224613f);
    p = fmaf(p,w,0.00943887047f);
    p = fmaf(p,w,1.00167406f);
    p = fmaf(p,w,2.83297682f);
  }
  return p*x;
}

// ---------------- W transpose: Wt[n][k] bf16 from W[k][n] f32 ----------------
__global__ __launch_bounds__(256) void wt_kernel(const float* __restrict__ W,
        short* __restrict__ Wt, int K, int Nn){
  __shared__ float tile[32][33];
  const int n0 = blockIdx.x*32, k0 = blockIdx.y*32;
  const int tx = threadIdx.x & 31, ty = threadIdx.x >> 5;   // 32 x 8
  #pragma unroll
  for (int i=0;i<4;++i)
    tile[ty+8*i][tx] = W[(size_t)(k0+ty+8*i)*Nn + n0 + tx];
  __syncthreads();
  #pragma unroll
  for (int i=0;i<4;++i)
    Wt[(size_t)(n0+ty+8*i)*K + k0 + tx] = (short)f2bu(tile[tx][ty+8*i]);
}

// ---------------- MFMA GEMM + fused attention coefficients ----------------
// C[M,OUT] = A[M,256] @ W[256,OUT]; A f32 or bf16, W via Wt[n][k] bf16.
// OUT=256: block covers 64 rows x 256 cols; wave w = cols 64w.. (= head w).
// OUT=64 : block covers 256 rows x 64 cols; wave w = rows 64w.., head 0.
// Per wave: 4x4 grid of 16x16 tiles, K-loop 8 steps of 32.
// LDS rows padded to 48 shorts (96 B): 16B-aligned b128, bounded conflicts.
template<int OUT, bool INBF>
__global__ __launch_bounds__(256) void gemm_mfma_kernel(const void* __restrict__ inp,
        const short* __restrict__ Wt, bf16* __restrict__ out,
        const float* __restrict__ a_s, const float* __restrict__ a_d,
        float* __restrict__ als, float* __restrict__ ald, int N){
  constexpr int M_BLK = (OUT==256) ? 64 : 256;
  constexpr int H = (OUT==256) ? 4 : 1;
  __shared__ short As[M_BLK*48];
  __shared__ short Bs[OUT*48];
  const int t = threadIdx.x;
  const int w = t>>6, lane = t&63;
  const int lm = lane&15, g = lane>>4;
  const int m0 = blockIdx.x * M_BLK;
  const int m_off = (OUT==256) ? 0 : w*64;
  const int n0    = (OUT==256) ? w*64 : 0;

  floatx4 acc[4][4] = {};

  for (int kk=0; kk<8; ++kk){
    const int k0 = kk*32;
    __syncthreads();
    // stage A (M_BLK x 32)
    for (int a = t; a < M_BLK*4; a += 256){
      int r = a>>2, c = a&3;
      int gr = m0 + r;
      uint4 v = make_uint4(0u,0u,0u,0u);
      if (gr < N){
        if constexpr (INBF){
          v = *(const uint4*)((const bf16*)inp + (size_t)gr*256 + k0 + c*8);
        } else {
          const float* p = (const float*)inp + (size_t)gr*256 + k0 + c*8;
          float4 f0 = *(const float4*)p;
          float4 f1 = *(const float4*)(p+4);
          v.x = (unsigned)f2bu(f0.x) | ((unsigned)f2bu(f0.y)<<16);
          v.y = (unsigned)f2bu(f0.z) | ((unsigned)f2bu(f0.w)<<16);
          v.z = (unsigned)f2bu(f1.x) | ((unsigned)f2bu(f1.y)<<16);
          v.w = (unsigned)f2bu(f1.z) | ((unsigned)f2bu(f1.w)<<16);
        }
      }
      *(uint4*)&As[r*48 + c*8] = v;
    }
    // stage B (OUT x 32) from Wt[n][k]
    for (int a = t; a < OUT*4; a += 256){
      int r = a>>2, c = a&3;
      uint4 v = *(const uint4*)(Wt + (size_t)r*256 + k0 + c*8);
      *(uint4*)&Bs[r*48 + c*8] = v;
    }
    __syncthreads();
    short8 af[4], bfr[4];
    #pragma unroll
    for (int mt=0;mt<4;++mt)
      af[mt] = *(const short8*)&As[(m_off + mt*16 + lm)*48 + g*8];
    #pragma unroll
    for (int nt=0;nt<4;++nt)
      bfr[nt] = *(const short8*)&Bs[(n0 + nt*16 + lm)*48 + g*8];
    #pragma unroll
    for (int mt=0;mt<4;++mt)
      #pragma unroll
      for (int nt=0;nt<4;++nt)
        acc[mt][nt] = __builtin_amdgcn_mfma_f32_16x16x32_bf16(af[mt], bfr[nt], acc[mt][nt], 0, 0, 0);
  }

  // epilogue: C-layout col = lm (+16nt+n0), row = g*4+reg (+16mt+m_off+m0)
  float asv[4], adv[4];
  #pragma unroll
  for (int nt=0;nt<4;++nt){
    asv[nt] = a_s[n0 + nt*16 + lm];
    adv[nt] = a_d[n0 + nt*16 + lm];
  }
  const int head = (OUT==256) ? w : 0;
  #pragma unroll
  for (int mt=0;mt<4;++mt){
    #pragma unroll
    for (int reg=0;reg<4;++reg){
      int gr = m0 + m_off + mt*16 + g*4 + reg;
      bool valid = gr < N;
      float ps = 0.f, pd = 0.f;
      #pragma unroll
      for (int nt=0;nt<4;++nt){
        float v = acc[mt][nt][reg];
        if (valid) out[(size_t)gr*OUT + n0 + nt*16 + lm] = __float2bfloat16(v);
        ps = fmaf(v, asv[nt], ps);
        pd = fmaf(v, adv[nt], pd);
      }
      #pragma unroll
      for (int o=1;o<16;o<<=1){ ps += __shfl_xor(ps,o); pd += __shfl_xor(pd,o); }
      if (lm==0 && valid){
        als[gr*H + head] = ps;
        ald[gr*H + head] = pd;
      }
    }
  }
}

// ---------------- scan-free CSR build (by destination, + self-loops) ----------------
__global__ void count_kernel(const int* __restrict__ ei, int* __restrict__ deg, int E){
  int e = blockIdx.x*blockDim.x+threadIdx.x; if (e<E) atomicAdd(&deg[ei[E+e]], 1);
}
__global__ void assign_kernel(const int* __restrict__ deg, int* __restrict__ off,
        int* __restrict__ cursor, int* __restrict__ total, int N){
  int i = blockIdx.x*blockDim.x+threadIdx.x;
  if (i<N){
    int d = deg[i] + 1;                       // +1 self-loop
    int start = atomicAdd(total, d);          // unordered segments: fine
    off[i] = start; cursor[i] = start;
  }
}
__global__ void fill_kernel(const int* __restrict__ ei, int* __restrict__ cursor,
        int* __restrict__ csr_src, int E, int N){
  int e = blockIdx.x*blockDim.x+threadIdx.x;
  if (e >= E+N) return;
  int s_ = (e < E) ? ei[e]   : e-E;
  int d_ = (e < E) ? ei[E+e] : e-E;
  int p = atomicAdd(&cursor[d_], 1);
  csr_src[p] = s_;
}

// ------- fused scatter-softmax + aggregate: 1 wave per node, uint2 gathers -------
template<int H, bool ELU>
__global__ __launch_bounds__(64) void aggregate_kernel(const bf16* __restrict__ h,
        const float* __restrict__ als, const float* __restrict__ ald,
        const int* __restrict__ off, const int* __restrict__ deg,
        const int* __restrict__ csr_src,
        const float* __restrict__ bias, bf16* __restrict__ out){
  const int n = blockIdx.x, lane = threadIdx.x;
  const int head = (H==4) ? (lane>>4) : 0;
  const int p0 = off[n], p1 = p0 + deg[n] + 1;
  const float aldn = ald[n*H + head];
  float m = -1e30f;
  for (int p=p0; p<p1; ++p){
    float e = leaky(als[csr_src[p]*H + head] + aldn);
    m = fmaxf(m, e);
  }
  if constexpr (H==4){
    float s = 0.f, a0=0.f,a1=0.f,a2=0.f,a3=0.f;
    for (int p=p0; p<p1; ++p){
      int src = csr_src[p];
      float e = leaky(als[src*4 + head] + aldn);
      float wgt = expf(e - m);
      s += wgt;
      uint2 hv = *(const uint2*)(h + (size_t)src*256 + 4*lane);
      a0 = fmaf(bflo(hv.x), wgt, a0);
      a1 = fmaf(bfhi(hv.x), wgt, a1);
      a2 = fmaf(bflo(hv.y), wgt, a2);
      a3 = fmaf(bfhi(hv.y), wgt, a3);
    }
    float inv = 1.f/(s + 1e-16f);
    float r0 = a0*inv + bias[4*lane+0];
    float r1 = a1*inv + bias[4*lane+1];
    float r2 = a2*inv + bias[4*lane+2];
    float r3 = a3*inv + bias[4*lane+3];
    if (ELU){
      r0 = (r0>0.f)?r0:expm1f(r0); r1 = (r1>0.f)?r1:expm1f(r1);
      r2 = (r2>0.f)?r2:expm1f(r2); r3 = (r3>0.f)?r3:expm1f(r3);
    }
    union { bf16 h4[4]; uint2 u; } pk;
    pk.h4[0]=__float2bfloat16(r0); pk.h4[1]=__float2bfloat16(r1);
    pk.h4[2]=__float2bfloat16(r2); pk.h4[3]=__float2bfloat16(r3);
    *(uint2*)(out + (size_t)n*256 + 4*lane) = pk.u;
  } else {
    float s = 0.f, acc = 0.f;
    for (int p=p0; p<p1; ++p){
      int src = csr_src[p];
      float e = leaky(als[src] + aldn);
      float wgt = expf(e - m);
      s += wgt;
      acc = fmaf(bf2f(h[(size_t)src*64 + lane]), wgt, acc);
    }
    float r = acc/(s + 1e-16f) + bias[lane];
    if (ELU) r = (r>0.f)?r:expm1f(r);
    out[(size_t)n*64 + lane] = __float2bfloat16(r);
  }
}

// ---------------- chunked pooling (batch sorted) ----------------
__global__ __launch_bounds__(64) void pool_kernel(const bf16* __restrict__ h3,
        const int* __restrict__ batch, float* __restrict__ psum, float* __restrict__ pcnt,
        int N, int chunk){
  int n0 = blockIdx.x*chunk;
  if (n0 >= N) return;
  int n1 = min(N, n0+chunk);
  int t = threadIdx.x;
  int gcur = batch[n0];
  float acc = 0.f, cnt = 0.f;
  for (int n=n0; n<n1; ++n){
    int g = batch[n];
    if (g != gcur){
      atomicAdd(&psum[gcur*64+t], acc);
      if (t==0) atomicAdd(&pcnt[gcur], cnt);
      acc = 0.f; cnt = 0.f; gcur = g;
    }
    acc += bf2f(h3[(size_t)n*64+t]);
    cnt += 1.f;
  }
  atomicAdd(&psum[gcur*64+t], acc);
  if (t==0) atomicAdd(&pcnt[gcur], cnt);
}

__global__ __launch_bounds__(64) void head_kernel(const float* __restrict__ psum,
        const float* __restrict__ pcnt,
        const float* __restrict__ Wmu, const float* __restrict__ bmu,
        const float* __restrict__ Wlv, const float* __restrict__ blv,
        float* __restrict__ out){
  int g = blockIdx.x, t = threadIdx.x;
  __shared__ float p[64];
  float cnt = fmaxf(pcnt[g], 1.0f);
  p[t] = psum[g*64+t] / cnt;
  __syncthreads();
  float mu = bmu[t], lv = blv[t];
  for (int k=0;k<64;++k){
    float pk = p[k];
    mu = fmaf(pk, Wmu[(size_t)k*64+t], mu);
    lv = fmaf(pk, Wlv[(size_t)k*64+t], lv);
  }
  // eps = jax.random.normal(key(42), (64,64)), jax_threefry_partitionable:
  //   per flat i: threefry2x32(key=(0,42), hi32(i)=0, lo32(i)=i), bits = x0'^x1'.
  int i = g*64 + t;
  unsigned x0 = 0u, x1 = (unsigned)i;
  threefry2x32(0u, 42u, x0, x1);
  unsigned bits = x0 ^ x1;
  float f = __uint_as_float((bits>>9) | 0x3F800000u) - 1.0f;   // [0,1)
  const float lo = __uint_as_float(0xBF7FFFFFu);               // -(1-2^-24)
  float u = fmaxf(lo, f*2.0f + lo);
  float eps = 1.41421356f * erfinv_approx(u);
  float z = mu + eps * expf(0.5f*lv);
  out[i]        = mu;
  out[4096 + i] = lv;
  out[8192 + i] = z;
}

// ---------------- launch ----------------
extern "C" void kernel_launch(void* const* d_in, const int* in_sizes, int n_in,
                              void* d_out, int out_size, void* d_ws, size_t ws_size,
                              hipStream_t stream){
  const float* x    = (const float*)d_in[0];
  const int*   ei   = (const int*)d_in[1];
  const int*   batch= (const int*)d_in[2];
  const float* W1   = (const float*)d_in[3];
  const float* a1s  = (const float*)d_in[4];
  const float* a1d  = (const float*)d_in[5];
  const float* b1   = (const float*)d_in[6];
  const float* W2   = (const float*)d_in[7];
  const float* a2s  = (const float*)d_in[8];
  const float* a2d  = (const float*)d_in[9];
  const float* b2   = (const float*)d_in[10];
  const float* W3   = (const float*)d_in[11];
  const float* a3s  = (const float*)d_in[12];
  const float* a3d  = (const float*)d_in[13];
  const float* b3   = (const float*)d_in[14];
  const float* Wmu  = (const float*)d_in[15];
  const float* bmu  = (const float*)d_in[16];
  const float* Wlv  = (const float*)d_in[17];
  const float* blv  = (const float*)d_in[18];
  float* out = (float*)d_out;

  const int N = N_NODES, E = N_EDGES;
  const int ET = E + N;

  char* ws = (char*)d_ws;
  size_t o = 0;
  auto alloc = [&](size_t bytes)->void*{
    void* p = ws + o; o += (bytes + 255) & ~(size_t)255; return p;
  };
  bf16*  hA      = (bf16*) alloc((size_t)N*256*2);   // 25.6 MB
  bf16*  hB      = (bf16*) alloc((size_t)N*256*2);   // 25.6 MB
  float* als     = (float*)alloc((size_t)N*4*4);
  float* ald     = (float*)alloc((size_t)N*4*4);
  int*   deg     = (int*)  alloc((size_t)N*4);
  int*   off     = (int*)  alloc((size_t)N*4);
  int*   cursor  = (int*)  alloc((size_t)N*4);
  int*   total   = (int*)  alloc(4);
  int*   csr_src = (int*)  alloc((size_t)ET*4);
  short* Wt1     = (short*)alloc(256*256*2);
  short* Wt2     = (short*)alloc(256*256*2);
  short* Wt3     = (short*)alloc(64*256*2);
  float* psum    = (float*)alloc(64*64*4);
  float* pcnt    = (float*)alloc(64*4);
  (void)ws_size; (void)n_in; (void)in_sizes; (void)out_size;

  const int TB = 256;
  const int egrid = (ET + TB - 1)/TB;

  // W transposes (bf16 [n][k])
  wt_kernel<<<dim3(8,8), 256, 0, stream>>>(W1, Wt1, 256, 256);
  wt_kernel<<<dim3(8,8), 256, 0, stream>>>(W2, Wt2, 256, 256);
  wt_kernel<<<dim3(2,8), 256, 0, stream>>>(W3, Wt3, 256, 64);

  // scan-free CSR by destination (rebuilt every call; ws re-poisoned per launch)
  hipMemsetAsync(deg, 0, (size_t)N*4, stream);
  hipMemsetAsync(total, 0, 4, stream);
  count_kernel<<<(E+TB-1)/TB, TB, 0, stream>>>(ei, deg, E);
  assign_kernel<<<(N+TB-1)/TB, TB, 0, stream>>>(deg, off, cursor, total, N);
  fill_kernel<<<egrid, TB, 0, stream>>>(ei, cursor, csr_src, E, N);

  // ---- layer 1: x(f32) @ W1, H=4, ELU ----
  gemm_mfma_kernel<256,false><<<(N+63)/64, 256, 0, stream>>>(x, Wt1, hB, a1s, a1d, als, ald, N);
  aggregate_kernel<4,true><<<N, 64, 0, stream>>>(hB, als, ald, off, deg, csr_src, b1, hA);

  // ---- layer 2: hA(bf16) @ W2, H=4, ELU ----
  gemm_mfma_kernel<256,true><<<(N+63)/64, 256, 0, stream>>>(hA, Wt2, hB, a2s, a2d, als, ald, N);
  aggregate_kernel<4,true><<<N, 64, 0, stream>>>(hB, als, ald, off, deg, csr_src, b2, hA);

  // ---- layer 3: hA(bf16) @ W3, H=1, no ELU ----
  gemm_mfma_kernel<64,true><<<(N+255)/256, 256, 0, stream>>>(hA, Wt3, hB, a3s, a3d, als, ald, N);
  aggregate_kernel<1,false><<<N, 64, 0, stream>>>(hB, als, ald, off, deg, csr_src, b3, hA);

  // ---- pool + VAE head ----
  hipMemsetAsync(psum, 0, 64*64*4, stream);
  hipMemsetAsync(pcnt, 0, 64*4, stream);
  const int PBLK = 512;
  const int chunk = (N + PBLK - 1)/PBLK;
  pool_kernel<<<PBLK, 64, 0, stream>>>(hA, batch, psum, pcnt, N, chunk);
  head_kernel<<<64, 64, 0, stream>>>(psum, pcnt, Wmu, bmu, Wlv, blv, out);
}

// Round 8
// 513.002 us; speedup vs baseline: 4.4268x; 1.2180x over previous
//
#include <hip/hip_runtime.h>
#include <hip/hip_bf16.h>
#include <cstdint>
#include <math.h>

// PathwayGraphEncoder: 3-layer GAT (+self-loops, scatter-softmax) -> mean pool
// -> VAE head with JAX partitionable-threefry eps.
// R8: single-pass aggregate (max-free softmax: exp can't overflow, |e|<~20;
// alpha = w/sum(w) identical), chunked edge-parallel weight precompute in LDS,
// unrolled uint2 gather. Merged wt launches + memsets (17->14 dispatches).

#define N_NODES 50000
#define N_EDGES 800000
#define NEG_SLOPE 0.2f

typedef __hip_bfloat16 bf16;
typedef short short8 __attribute__((ext_vector_type(8)));
typedef float floatx4 __attribute__((ext_vector_type(4)));

__device__ __forceinline__ float bf2f(bf16 v){ return __bfloat162float(v); }
__device__ __forceinline__ float bflo(unsigned u){ union{unsigned u; float f;} c; c.u = u<<16; return c.f; }
__device__ __forceinline__ float bfhi(unsigned u){ union{unsigned u; float f;} c; c.u = u & 0xFFFF0000u; return c.f; }
__device__ __forceinline__ float leaky(float v){ return v>0.f ? v : NEG_SLOPE*v; }
__device__ __forceinline__ unsigned short f2bu(float f){
  union{ bf16 b; unsigned short u; } c; c.b = __float2bfloat16(f); return c.u;
}

// ---------------- threefry2x32 (JAX-compatible) ----------------
__device__ __forceinline__ void tf_round(unsigned& x0, unsigned& x1, int r){
  x0 += x1; x1 = (x1<<r)|(x1>>(32-r)); x1 ^= x0;
}
__device__ __forceinline__ void threefry2x32(unsigned k0, unsigned k1, unsigned& x0, unsigned& x1){
  unsigned ks2 = k0 ^ k1 ^ 0x1BD11BDAu;
  x0 += k0; x1 += k1;
  tf_round(x0,x1,13); tf_round(x0,x1,15); tf_round(x0,x1,26); tf_round(x0,x1,6);
  x0 += k1; x1 += ks2 + 1u;
  tf_round(x0,x1,17); tf_round(x0,x1,29); tf_round(x0,x1,16); tf_round(x0,x1,24);
  x0 += ks2; x1 += k0 + 2u;
  tf_round(x0,x1,13); tf_round(x0,x1,15); tf_round(x0,x1,26); tf_round(x0,x1,6);
  x0 += k0; x1 += k1 + 3u;
  tf_round(x0,x1,17); tf_round(x0,x1,29); tf_round(x0,x1,16); tf_round(x0,x1,24);
  x0 += k1; x1 += ks2 + 4u;
  tf_round(x0,x1,13); tf_round(x0,x1,15); tf_round(x0,x1,26); tf_round(x0,x1,6);
  x0 += ks2; x1 += k0 + 5u;
}

// Giles single-precision erfinv (XLA ErfInv32 coefficients)
__device__ __forceinline__ float erfinv_approx(float x){
  float w = -log1pf(-x*x);
  float p;
  if (w < 5.0f){
    w = w - 2.5f;
    p = 2.81022636e-08f;
    p = fmaf(p,w,3.43273939e-07f);
    p = fmaf(p,w,-3.5233877e-06f);
    p = fmaf(p,w,-4.39150654e-06f);
    p = fmaf(p,w,0.00021858087f);
    p = fmaf(p,w,-0.00125372503f);
    p = fmaf(p,w,-0.00417768164f);
    p = fmaf(p,w,0.246640727f);
    p = fmaf(p,w,1.50140941f);
  } else {
    w = sqrtf(w) - 3.0f;
    p = -0.000200214257f;
    p = fmaf(p,w,0.000100950558f);
    p = fmaf(p,w,0.00134934322f);
    p = fmaf(p,w,-0.00367342844f);
    p = fmaf(p,w,0.00573950773f);
    p = fmaf(p,w,-0.0076224613f);
    p = fmaf(p,w,0.00943887047f);
    p = fmaf(p,w,1.00167406f);
    p = fmaf(p,w,2.83297682f);
  }
  return p*x;
}

// ------- W transposes (all 3 in one launch): Wt[n][k] bf16 from W[k][n] f32 -------
__global__ __launch_bounds__(256) void wt_all_kernel(
        const float* __restrict__ W1, const float* __restrict__ W2,
        const float* __restrict__ W3, short* __restrict__ Wt1,
        short* __restrict__ Wt2, short* __restrict__ Wt3){
  const float* W; short* Wt; int Nn;
  if (blockIdx.z == 0){ W = W1; Wt = Wt1; Nn = 256; }
  else if (blockIdx.z == 1){ W = W2; Wt = Wt2; Nn = 256; }
  else { W = W3; Wt = Wt3; Nn = 64; }
  const int n0 = blockIdx.x*32, k0 = blockIdx.y*32;
  if (n0 >= Nn) return;
  __shared__ float tile[32][33];
  const int tx = threadIdx.x & 31, ty = threadIdx.x >> 5;   // 32 x 8
  #pragma unroll
  for (int i=0;i<4;++i)
    tile[ty+8*i][tx] = W[(size_t)(k0+ty+8*i)*Nn + n0 + tx];
  __syncthreads();
  #pragma unroll
  for (int i=0;i<4;++i)
    Wt[(size_t)(n0+ty+8*i)*256 + k0 + tx] = (short)f2bu(tile[tx][ty+8*i]);
}

// ---------------- MFMA GEMM + fused attention coefficients ----------------
template<int OUT, bool INBF>
__global__ __launch_bounds__(256) void gemm_mfma_kernel(const void* __restrict__ inp,
        const short* __restrict__ Wt, bf16* __restrict__ out,
        const float* __restrict__ a_s, const float* __restrict__ a_d,
        float* __restrict__ als, float* __restrict__ ald, int N){
  constexpr int M_BLK = (OUT==256) ? 64 : 256;
  constexpr int H = (OUT==256) ? 4 : 1;
  __shared__ short As[M_BLK*48];
  __shared__ short Bs[OUT*48];
  const int t = threadIdx.x;
  const int w = t>>6, lane = t&63;
  const int lm = lane&15, g = lane>>4;
  const int m0 = blockIdx.x * M_BLK;
  const int m_off = (OUT==256) ? 0 : w*64;
  const int n0    = (OUT==256) ? w*64 : 0;

  floatx4 acc[4][4] = {};

  for (int kk=0; kk<8; ++kk){
    const int k0 = kk*32;
    __syncthreads();
    for (int a = t; a < M_BLK*4; a += 256){
      int r = a>>2, c = a&3;
      int gr = m0 + r;
      uint4 v = make_uint4(0u,0u,0u,0u);
      if (gr < N){
        if constexpr (INBF){
          v = *(const uint4*)((const bf16*)inp + (size_t)gr*256 + k0 + c*8);
        } else {
          const float* p = (const float*)inp + (size_t)gr*256 + k0 + c*8;
          float4 f0 = *(const float4*)p;
          float4 f1 = *(const float4*)(p+4);
          v.x = (unsigned)f2bu(f0.x) | ((unsigned)f2bu(f0.y)<<16);
          v.y = (unsigned)f2bu(f0.z) | ((unsigned)f2bu(f0.w)<<16);
          v.z = (unsigned)f2bu(f1.x) | ((unsigned)f2bu(f1.y)<<16);
          v.w = (unsigned)f2bu(f1.z) | ((unsigned)f2bu(f1.w)<<16);
        }
      }
      *(uint4*)&As[r*48 + c*8] = v;
    }
    for (int a = t; a < OUT*4; a += 256){
      int r = a>>2, c = a&3;
      uint4 v = *(const uint4*)(Wt + (size_t)r*256 + k0 + c*8);
      *(uint4*)&Bs[r*48 + c*8] = v;
    }
    __syncthreads();
    short8 af[4], bfr[4];
    #pragma unroll
    for (int mt=0;mt<4;++mt)
      af[mt] = *(const short8*)&As[(m_off + mt*16 + lm)*48 + g*8];
    #pragma unroll
    for (int nt=0;nt<4;++nt)
      bfr[nt] = *(const short8*)&Bs[(n0 + nt*16 + lm)*48 + g*8];
    #pragma unroll
    for (int mt=0;mt<4;++mt)
      #pragma unroll
      for (int nt=0;nt<4;++nt)
        acc[mt][nt] = __builtin_amdgcn_mfma_f32_16x16x32_bf16(af[mt], bfr[nt], acc[mt][nt], 0, 0, 0);
  }

  float asv[4], adv[4];
  #pragma unroll
  for (int nt=0;nt<4;++nt){
    asv[nt] = a_s[n0 + nt*16 + lm];
    adv[nt] = a_d[n0 + nt*16 + lm];
  }
  const int head = (OUT==256) ? w : 0;
  #pragma unroll
  for (int mt=0;mt<4;++mt){
    #pragma unroll
    for (int reg=0;reg<4;++reg){
      int gr = m0 + m_off + mt*16 + g*4 + reg;
      bool valid = gr < N;
      float ps = 0.f, pd = 0.f;
      #pragma unroll
      for (int nt=0;nt<4;++nt){
        float v = acc[mt][nt][reg];
        if (valid) out[(size_t)gr*OUT + n0 + nt*16 + lm] = __float2bfloat16(v);
        ps = fmaf(v, asv[nt], ps);
        pd = fmaf(v, adv[nt], pd);
      }
      #pragma unroll
      for (int o=1;o<16;o<<=1){ ps += __shfl_xor(ps,o); pd += __shfl_xor(pd,o); }
      if (lm==0 && valid){
        als[gr*H + head] = ps;
        ald[gr*H + head] = pd;
      }
    }
  }
}

// ---------------- scan-free CSR build (by destination, + self-loops) ----------------
__global__ void count_kernel(const int* __restrict__ ei, int* __restrict__ deg, int E){
  int e = blockIdx.x*blockDim.x+threadIdx.x; if (e<E) atomicAdd(&deg[ei[E+e]], 1);
}
__global__ void assign_kernel(const int* __restrict__ deg, int* __restrict__ off,
        int* __restrict__ cursor, int* __restrict__ total, int N){
  int i = blockIdx.x*blockDim.x+threadIdx.x;
  if (i<N){
    int d = deg[i] + 1;                       // +1 self-loop
    int start = atomicAdd(total, d);          // unordered segments: fine
    off[i] = start; cursor[i] = start;
  }
}
__global__ void fill_kernel(const int* __restrict__ ei, int* __restrict__ cursor,
        int* __restrict__ csr_src, int E, int N){
  int e = blockIdx.x*blockDim.x+threadIdx.x;
  if (e >= E+N) return;
  int s_ = (e < E) ? ei[e]   : e-E;
  int d_ = (e < E) ? ei[E+e] : e-E;
  int p = atomicAdd(&cursor[d_], 1);
  csr_src[p] = s_;
}

// ------- single-pass scatter-softmax + aggregate, H=4 (1 wave/node) -------
// Max-free softmax: out = (sum_e w_e h[src_e]) / (sum_e w_e), w_e=exp(leaky(.)).
template<bool ELU>
__global__ __launch_bounds__(64) void aggregate4_kernel(const bf16* __restrict__ h,
        const float* __restrict__ als, const float* __restrict__ ald,
        const int* __restrict__ off, const int* __restrict__ deg,
        const int* __restrict__ csr_src,
        const float* __restrict__ bias, bf16* __restrict__ out){
  __shared__ int   s_src[64];
  __shared__ float s_w[64][4];
  const int n = blockIdx.x, lane = threadIdx.x;
  const int head = lane>>4;
  const int p0 = off[n], cnt = deg[n]+1;
  const float4 aldn4 = *(const float4*)(ald + n*4);
  float ssum = 0.f, a0=0.f, a1=0.f, a2=0.f, a3=0.f;
  for (int c=0; c<cnt; c+=64){
    int e = c + lane;
    if (e < cnt){
      int src = csr_src[p0+e];
      s_src[lane] = src;
      float4 av = *(const float4*)(als + src*4);
      float4 w4;
      w4.x = expf(leaky(av.x + aldn4.x));
      w4.y = expf(leaky(av.y + aldn4.y));
      w4.z = expf(leaky(av.z + aldn4.z));
      w4.w = expf(leaky(av.w + aldn4.w));
      *(float4*)&s_w[lane][0] = w4;
    }
    int ce = min(64, cnt - c);
    int i = 0;
    for (; i+2<=ce; i+=2){   // 2 gathers in flight
      int src0 = s_src[i], src1 = s_src[i+1];
      float w0 = s_w[i][head], w1 = s_w[i+1][head];
      uint2 hv0 = *(const uint2*)(h + (size_t)src0*256 + 4*lane);
      uint2 hv1 = *(const uint2*)(h + (size_t)src1*256 + 4*lane);
      ssum += w0 + w1;
      a0 = fmaf(bflo(hv0.x), w0, a0); a1 = fmaf(bfhi(hv0.x), w0, a1);
      a2 = fmaf(bflo(hv0.y), w0, a2); a3 = fmaf(bfhi(hv0.y), w0, a3);
      a0 = fmaf(bflo(hv1.x), w1, a0); a1 = fmaf(bfhi(hv1.x), w1, a1);
      a2 = fmaf(bflo(hv1.y), w1, a2); a3 = fmaf(bfhi(hv1.y), w1, a3);
    }
    if (i < ce){
      int src0 = s_src[i];
      float w0 = s_w[i][head];
      uint2 hv0 = *(const uint2*)(h + (size_t)src0*256 + 4*lane);
      ssum += w0;
      a0 = fmaf(bflo(hv0.x), w0, a0); a1 = fmaf(bfhi(hv0.x), w0, a1);
      a2 = fmaf(bflo(hv0.y), w0, a2); a3 = fmaf(bfhi(hv0.y), w0, a3);
    }
  }
  float inv = 1.f/(ssum + 1e-16f);
  float r0 = a0*inv + bias[4*lane+0];
  float r1 = a1*inv + bias[4*lane+1];
  float r2 = a2*inv + bias[4*lane+2];
  float r3 = a3*inv + bias[4*lane+3];
  if (ELU){
    r0 = (r0>0.f)?r0:expm1f(r0); r1 = (r1>0.f)?r1:expm1f(r1);
    r2 = (r2>0.f)?r2:expm1f(r2); r3 = (r3>0.f)?r3:expm1f(r3);
  }
  union { bf16 h4[4]; uint2 u; } pk;
  pk.h4[0]=__float2bfloat16(r0); pk.h4[1]=__float2bfloat16(r1);
  pk.h4[2]=__float2bfloat16(r2); pk.h4[3]=__float2bfloat16(r3);
  *(uint2*)(out + (size_t)n*256 + 4*lane) = pk.u;
}

// ------- single-pass scatter-softmax + aggregate, H=1 (1 wave/node) -------
__global__ __launch_bounds__(64) void aggregate1_kernel(const bf16* __restrict__ h,
        const float* __restrict__ als, const float* __restrict__ ald,
        const int* __restrict__ off, const int* __restrict__ deg,
        const int* __restrict__ csr_src,
        const float* __restrict__ bias, bf16* __restrict__ out){
  __shared__ int   s_src[64];
  __shared__ float s_w[64];
  const int n = blockIdx.x, lane = threadIdx.x;
  const int p0 = off[n], cnt = deg[n]+1;
  const float aldn = ald[n];
  float ssum = 0.f, acc = 0.f;
  for (int c=0; c<cnt; c+=64){
    int e = c + lane;
    if (e < cnt){
      int src = csr_src[p0+e];
      s_src[lane] = src;
      s_w[lane] = expf(leaky(als[src] + aldn));
    }
    int ce = min(64, cnt - c);
    int i = 0;
    for (; i+2<=ce; i+=2){
      int src0 = s_src[i], src1 = s_src[i+1];
      float w0 = s_w[i], w1 = s_w[i+1];
      float h0 = bf2f(h[(size_t)src0*64 + lane]);
      float h1 = bf2f(h[(size_t)src1*64 + lane]);
      ssum += w0 + w1;
      acc = fmaf(h0, w0, acc);
      acc = fmaf(h1, w1, acc);
    }
    if (i < ce){
      int src0 = s_src[i];
      float w0 = s_w[i];
      ssum += w0;
      acc = fmaf(bf2f(h[(size_t)src0*64 + lane]), w0, acc);
    }
  }
  float r = acc/(ssum + 1e-16f) + bias[lane];
  out[(size_t)n*64 + lane] = __float2bfloat16(r);
}

// ---------------- chunked pooling (batch sorted) ----------------
__global__ __launch_bounds__(64) void pool_kernel(const bf16* __restrict__ h3,
        const int* __restrict__ batch, float* __restrict__ psum, float* __restrict__ pcnt,
        int N, int chunk){
  int n0 = blockIdx.x*chunk;
  if (n0 >= N) return;
  int n1 = min(N, n0+chunk);
  int t = threadIdx.x;
  int gcur = batch[n0];
  float acc = 0.f, cnt = 0.f;
  for (int n=n0; n<n1; ++n){
    int g = batch[n];
    if (g != gcur){
      atomicAdd(&psum[gcur*64+t], acc);
      if (t==0) atomicAdd(&pcnt[gcur], cnt);
      acc = 0.f; cnt = 0.f; gcur = g;
    }
    acc += bf2f(h3[(size_t)n*64+t]);
    cnt += 1.f;
  }
  atomicAdd(&psum[gcur*64+t], acc);
  if (t==0) atomicAdd(&pcnt[gcur], cnt);
}

__global__ __launch_bounds__(64) void head_kernel(const float* __restrict__ psum,
        const float* __restrict__ pcnt,
        const float* __restrict__ Wmu, const float* __restrict__ bmu,
        const float* __restrict__ Wlv, const float* __restrict__ blv,
        float* __restrict__ out){
  int g = blockIdx.x, t = threadIdx.x;
  __shared__ float p[64];
  float cnt = fmaxf(pcnt[g], 1.0f);
  p[t] = psum[g*64+t] / cnt;
  __syncthreads();
  float mu = bmu[t], lv = blv[t];
  for (int k=0;k<64;++k){
    float pk = p[k];
    mu = fmaf(pk, Wmu[(size_t)k*64+t], mu);
    lv = fmaf(pk, Wlv[(size_t)k*64+t], lv);
  }
  int i = g*64 + t;
  unsigned x0 = 0u, x1 = (unsigned)i;
  threefry2x32(0u, 42u, x0, x1);
  unsigned bits = x0 ^ x1;
  float f = __uint_as_float((bits>>9) | 0x3F800000u) - 1.0f;   // [0,1)
  const float lo = __uint_as_float(0xBF7FFFFFu);               // -(1-2^-24)
  float u = fmaxf(lo, f*2.0f + lo);
  float eps = 1.41421356f * erfinv_approx(u);
  float z = mu + eps * expf(0.5f*lv);
  out[i]        = mu;
  out[4096 + i] = lv;
  out[8192 + i] = z;
}

// ---------------- launch ----------------
extern "C" void kernel_launch(void* const* d_in, const int* in_sizes, int n_in,
                              void* d_out, int out_size, void* d_ws, size_t ws_size,
                              hipStream_t stream){
  const float* x    = (const float*)d_in[0];
  const int*   ei   = (const int*)d_in[1];
  const int*   batch= (const int*)d_in[2];
  const float* W1   = (const float*)d_in[3];
  const float* a1s  = (const float*)d_in[4];
  const float* a1d  = (const float*)d_in[5];
  const float* b1   = (const float*)d_in[6];
  const float* W2   = (const float*)d_in[7];
  const float* a2s  = (const float*)d_in[8];
  const float* a2d  = (const float*)d_in[9];
  const float* b2   = (const float*)d_in[10];
  const float* W3   = (const float*)d_in[11];
  const float* a3s  = (const float*)d_in[12];
  const float* a3d  = (const float*)d_in[13];
  const float* b3   = (const float*)d_in[14];
  const float* Wmu  = (const float*)d_in[15];
  const float* bmu  = (const float*)d_in[16];
  const float* Wlv  = (const float*)d_in[17];
  const float* blv  = (const float*)d_in[18];
  float* out = (float*)d_out;

  const int N = N_NODES, E = N_EDGES;
  const int ET = E + N;

  char* ws = (char*)d_ws;
  size_t o = 0;
  auto alloc = [&](size_t bytes)->void*{
    void* p = ws + o; o += (bytes + 255) & ~(size_t)255; return p;
  };
  bf16*  hA      = (bf16*) alloc((size_t)N*256*2);   // 25.6 MB
  bf16*  hB      = (bf16*) alloc((size_t)N*256*2);   // 25.6 MB
  float* als     = (float*)alloc((size_t)N*4*4);
  float* ald     = (float*)alloc((size_t)N*4*4);
  int*   deg     = (int*)  alloc((size_t)(N+1)*4);   // deg[N] = total
  int*   total   = deg + N;
  int*   off     = (int*)  alloc((size_t)N*4);
  int*   cursor  = (int*)  alloc((size_t)N*4);
  int*   csr_src = (int*)  alloc((size_t)ET*4);
  short* Wt1     = (short*)alloc(256*256*2);
  short* Wt2     = (short*)alloc(256*256*2);
  short* Wt3     = (short*)alloc(64*256*2);
  float* psum    = (float*)alloc(64*64*4 + 64*4);    // psum + pcnt contiguous
  float* pcnt    = psum + 64*64;
  (void)ws_size; (void)n_in; (void)in_sizes; (void)out_size;

  const int TB = 256;
  const int egrid = (ET + TB - 1)/TB;

  // W transposes (bf16 [n][k]) — single launch
  wt_all_kernel<<<dim3(8,8,3), 256, 0, stream>>>(W1, W2, W3, Wt1, Wt2, Wt3);

  // scan-free CSR by destination (rebuilt every call; ws re-poisoned per launch)
  hipMemsetAsync(deg, 0, (size_t)(N+1)*4, stream);
  count_kernel<<<(E+TB-1)/TB, TB, 0, stream>>>(ei, deg, E);
  assign_kernel<<<(N+TB-1)/TB, TB, 0, stream>>>(deg, off, cursor, total, N);
  fill_kernel<<<egrid, TB, 0, stream>>>(ei, cursor, csr_src, E, N);

  // ---- layer 1: x(f32) @ W1, H=4, ELU ----
  gemm_mfma_kernel<256,false><<<(N+63)/64, 256, 0, stream>>>(x, Wt1, hB, a1s, a1d, als, ald, N);
  aggregate4_kernel<true><<<N, 64, 0, stream>>>(hB, als, ald, off, deg, csr_src, b1, hA);

  // ---- layer 2: hA(bf16) @ W2, H=4, ELU ----
  gemm_mfma_kernel<256,true><<<(N+63)/64, 256, 0, stream>>>(hA, Wt2, hB, a2s, a2d, als, ald, N);
  aggregate4_kernel<true><<<N, 64, 0, stream>>>(hB, als, ald, off, deg, csr_src, b2, hA);

  // ---- layer 3: hA(bf16) @ W3, H=1, no ELU ----
  gemm_mfma_kernel<64,true><<<(N+255)/256, 256, 0, stream>>>(hA, Wt3, hB, a3s, a3d, als, ald, N);
  aggregate1_kernel<<<N, 64, 0, stream>>>(hB, als, ald, off, deg, csr_src, b3, hA);

  // ---- pool + VAE head ----
  hipMemsetAsync(psum, 0, 64*64*4 + 64*4, stream);
  const int PBLK = 512;
  const int chunk = (N + PBLK - 1)/PBLK;
  pool_kernel<<<PBLK, 64, 0, stream>>>(hA, batch, psum, pcnt, N, chunk);
  head_kernel<<<64, 64, 0, stream>>>(psum, pcnt, Wmu, bmu, Wlv, blv, out);
}

// Round 9
// 500.303 us; speedup vs baseline: 4.5392x; 1.0254x over previous
//
#include <hip/hip_runtime.h>
#include <hip/hip_bf16.h>
#include <cstdint>
#include <math.h>

// PathwayGraphEncoder: 3-layer GAT (+self-loops, scatter-softmax) -> mean pool
// -> VAE head with JAX partitionable-threefry eps.
// R9: wide gather in aggregates. agg4: uint4/lane => 2 h-rows per wave-instr,
// 4 loads in flight, parity-split accumulators + shfl_xor(32) combine.
// agg1: uint2/lane => 4 rows per instr, shfl_xor(16,32) combine.

#define N_NODES 50000
#define N_EDGES 800000
#define NEG_SLOPE 0.2f

typedef __hip_bfloat16 bf16;
typedef short short8 __attribute__((ext_vector_type(8)));
typedef float floatx4 __attribute__((ext_vector_type(4)));

__device__ __forceinline__ float bf2f(bf16 v){ return __bfloat162float(v); }
__device__ __forceinline__ float bflo(unsigned u){ union{unsigned u; float f;} c; c.u = u<<16; return c.f; }
__device__ __forceinline__ float bfhi(unsigned u){ union{unsigned u; float f;} c; c.u = u & 0xFFFF0000u; return c.f; }
__device__ __forceinline__ float leaky(float v){ return v>0.f ? v : NEG_SLOPE*v; }
__device__ __forceinline__ unsigned short f2bu(float f){
  union{ bf16 b; unsigned short u; } c; c.b = __float2bfloat16(f); return c.u;
}

// ---------------- threefry2x32 (JAX-compatible) ----------------
__device__ __forceinline__ void tf_round(unsigned& x0, unsigned& x1, int r){
  x0 += x1; x1 = (x1<<r)|(x1>>(32-r)); x1 ^= x0;
}
__device__ __forceinline__ void threefry2x32(unsigned k0, unsigned k1, unsigned& x0, unsigned& x1){
  unsigned ks2 = k0 ^ k1 ^ 0x1BD11BDAu;
  x0 += k0; x1 += k1;
  tf_round(x0,x1,13); tf_round(x0,x1,15); tf_round(x0,x1,26); tf_round(x0,x1,6);
  x0 += k1; x1 += ks2 + 1u;
  tf_round(x0,x1,17); tf_round(x0,x1,29); tf_round(x0,x1,16); tf_round(x0,x1,24);
  x0 += ks2; x1 += k0 + 2u;
  tf_round(x0,x1,13); tf_round(x0,x1,15); tf_round(x0,x1,26); tf_round(x0,x1,6);
  x0 += k0; x1 += k1 + 3u;
  tf_round(x0,x1,17); tf_round(x0,x1,29); tf_round(x0,x1,16); tf_round(x0,x1,24);
  x0 += k1; x1 += ks2 + 4u;
  tf_round(x0,x1,13); tf_round(x0,x1,15); tf_round(x0,x1,26); tf_round(x0,x1,6);
  x0 += ks2; x1 += k0 + 5u;
}

// Giles single-precision erfinv (XLA ErfInv32 coefficients)
__device__ __forceinline__ float erfinv_approx(float x){
  float w = -log1pf(-x*x);
  float p;
  if (w < 5.0f){
    w = w - 2.5f;
    p = 2.81022636e-08f;
    p = fmaf(p,w,3.43273939e-07f);
    p = fmaf(p,w,-3.5233877e-06f);
    p = fmaf(p,w,-4.39150654e-06f);
    p = fmaf(p,w,0.00021858087f);
    p = fmaf(p,w,-0.00125372503f);
    p = fmaf(p,w,-0.00417768164f);
    p = fmaf(p,w,0.246640727f);
    p = fmaf(p,w,1.50140941f);
  } else {
    w = sqrtf(w) - 3.0f;
    p = -0.000200214257f;
    p = fmaf(p,w,0.000100950558f);
    p = fmaf(p,w,0.00134934322f);
    p = fmaf(p,w,-0.00367342844f);
    p = fmaf(p,w,0.00573950773f);
    p = fmaf(p,w,-0.0076224613f);
    p = fmaf(p,w,0.00943887047f);
    p = fmaf(p,w,1.00167406f);
    p = fmaf(p,w,2.83297682f);
  }
  return p*x;
}

// ------- W transposes (all 3 in one launch): Wt[n][k] bf16 from W[k][n] f32 -------
__global__ __launch_bounds__(256) void wt_all_kernel(
        const float* __restrict__ W1, const float* __restrict__ W2,
        const float* __restrict__ W3, short* __restrict__ Wt1,
        short* __restrict__ Wt2, short* __restrict__ Wt3){
  const float* W; short* Wt; int Nn;
  if (blockIdx.z == 0){ W = W1; Wt = Wt1; Nn = 256; }
  else if (blockIdx.z == 1){ W = W2; Wt = Wt2; Nn = 256; }
  else { W = W3; Wt = Wt3; Nn = 64; }
  const int n0 = blockIdx.x*32, k0 = blockIdx.y*32;
  if (n0 >= Nn) return;
  __shared__ float tile[32][33];
  const int tx = threadIdx.x & 31, ty = threadIdx.x >> 5;   // 32 x 8
  #pragma unroll
  for (int i=0;i<4;++i)
    tile[ty+8*i][tx] = W[(size_t)(k0+ty+8*i)*Nn + n0 + tx];
  __syncthreads();
  #pragma unroll
  for (int i=0;i<4;++i)
    Wt[(size_t)(n0+ty+8*i)*256 + k0 + tx] = (short)f2bu(tile[tx][ty+8*i]);
}

// ---------------- MFMA GEMM + fused attention coefficients ----------------
template<int OUT, bool INBF>
__global__ __launch_bounds__(256) void gemm_mfma_kernel(const void* __restrict__ inp,
        const short* __restrict__ Wt, bf16* __restrict__ out,
        const float* __restrict__ a_s, const float* __restrict__ a_d,
        float* __restrict__ als, float* __restrict__ ald, int N){
  constexpr int M_BLK = (OUT==256) ? 64 : 256;
  constexpr int H = (OUT==256) ? 4 : 1;
  __shared__ short As[M_BLK*48];
  __shared__ short Bs[OUT*48];
  const int t = threadIdx.x;
  const int w = t>>6, lane = t&63;
  const int lm = lane&15, g = lane>>4;
  const int m0 = blockIdx.x * M_BLK;
  const int m_off = (OUT==256) ? 0 : w*64;
  const int n0    = (OUT==256) ? w*64 : 0;

  floatx4 acc[4][4] = {};

  for (int kk=0; kk<8; ++kk){
    const int k0 = kk*32;
    __syncthreads();
    for (int a = t; a < M_BLK*4; a += 256){
      int r = a>>2, c = a&3;
      int gr = m0 + r;
      uint4 v = make_uint4(0u,0u,0u,0u);
      if (gr < N){
        if constexpr (INBF){
          v = *(const uint4*)((const bf16*)inp + (size_t)gr*256 + k0 + c*8);
        } else {
          const float* p = (const float*)inp + (size_t)gr*256 + k0 + c*8;
          float4 f0 = *(const float4*)p;
          float4 f1 = *(const float4*)(p+4);
          v.x = (unsigned)f2bu(f0.x) | ((unsigned)f2bu(f0.y)<<16);
          v.y = (unsigned)f2bu(f0.z) | ((unsigned)f2bu(f0.w)<<16);
          v.z = (unsigned)f2bu(f1.x) | ((unsigned)f2bu(f1.y)<<16);
          v.w = (unsigned)f2bu(f1.z) | ((unsigned)f2bu(f1.w)<<16);
        }
      }
      *(uint4*)&As[r*48 + c*8] = v;
    }
    for (int a = t; a < OUT*4; a += 256){
      int r = a>>2, c = a&3;
      uint4 v = *(const uint4*)(Wt + (size_t)r*256 + k0 + c*8);
      *(uint4*)&Bs[r*48 + c*8] = v;
    }
    __syncthreads();
    short8 af[4], bfr[4];
    #pragma unroll
    for (int mt=0;mt<4;++mt)
      af[mt] = *(const short8*)&As[(m_off + mt*16 + lm)*48 + g*8];
    #pragma unroll
    for (int nt=0;nt<4;++nt)
      bfr[nt] = *(const short8*)&Bs[(n0 + nt*16 + lm)*48 + g*8];
    #pragma unroll
    for (int mt=0;mt<4;++mt)
      #pragma unroll
      for (int nt=0;nt<4;++nt)
        acc[mt][nt] = __builtin_amdgcn_mfma_f32_16x16x32_bf16(af[mt], bfr[nt], acc[mt][nt], 0, 0, 0);
  }

  float asv[4], adv[4];
  #pragma unroll
  for (int nt=0;nt<4;++nt){
    asv[nt] = a_s[n0 + nt*16 + lm];
    adv[nt] = a_d[n0 + nt*16 + lm];
  }
  const int head = (OUT==256) ? w : 0;
  #pragma unroll
  for (int mt=0;mt<4;++mt){
    #pragma unroll
    for (int reg=0;reg<4;++reg){
      int gr = m0 + m_off + mt*16 + g*4 + reg;
      bool valid = gr < N;
      float ps = 0.f, pd = 0.f;
      #pragma unroll
      for (int nt=0;nt<4;++nt){
        float v = acc[mt][nt][reg];
        if (valid) out[(size_t)gr*OUT + n0 + nt*16 + lm] = __float2bfloat16(v);
        ps = fmaf(v, asv[nt], ps);
        pd = fmaf(v, adv[nt], pd);
      }
      #pragma unroll
      for (int o=1;o<16;o<<=1){ ps += __shfl_xor(ps,o); pd += __shfl_xor(pd,o); }
      if (lm==0 && valid){
        als[gr*H + head] = ps;
        ald[gr*H + head] = pd;
      }
    }
  }
}

// ---------------- scan-free CSR build (by destination, + self-loops) ----------------
__global__ void count_kernel(const int* __restrict__ ei, int* __restrict__ deg, int E){
  int e = blockIdx.x*blockDim.x+threadIdx.x; if (e<E) atomicAdd(&deg[ei[E+e]], 1);
}
__global__ void assign_kernel(const int* __restrict__ deg, int* __restrict__ off,
        int* __restrict__ cursor, int* __restrict__ total, int N){
  int i = blockIdx.x*blockDim.x+threadIdx.x;
  if (i<N){
    int d = deg[i] + 1;                       // +1 self-loop
    int start = atomicAdd(total, d);          // unordered segments: fine
    off[i] = start; cursor[i] = start;
  }
}
__global__ void fill_kernel(const int* __restrict__ ei, int* __restrict__ cursor,
        int* __restrict__ csr_src, int E, int N){
  int e = blockIdx.x*blockDim.x+threadIdx.x;
  if (e >= E+N) return;
  int s_ = (e < E) ? ei[e]   : e-E;
  int d_ = (e < E) ? ei[E+e] : e-E;
  int p = atomicAdd(&cursor[d_], 1);
  csr_src[p] = s_;
}

// ------- single-pass scatter-softmax + aggregate, H=4 (1 wave/node) -------
// lane = parity r (lane>>5) x feature-octet f (lane&31); uint4 loads => 2 rows
// per wave-instruction, 4 in flight; parity partials combined via shfl_xor(32).
template<bool ELU>
__global__ __launch_bounds__(64) void aggregate4_kernel(const bf16* __restrict__ h,
        const float* __restrict__ als, const float* __restrict__ ald,
        const int* __restrict__ off, const int* __restrict__ deg,
        const int* __restrict__ csr_src,
        const float* __restrict__ bias, bf16* __restrict__ out){
  __shared__ int   s_src[64];
  __shared__ float s_w[64][4];
  const int n = blockIdx.x, lane = threadIdx.x;
  const int r = lane>>5;            // edge parity (0/1)
  const int f = lane&31;            // feature octet: features f*8..f*8+7
  const int head = f>>3;
  const int p0 = off[n], cnt = deg[n]+1;
  const float4 aldn4 = *(const float4*)(ald + n*4);
  float ssum = 0.f;
  float acc[8] = {};
  for (int c=0; c<cnt; c+=64){
    int e = c + lane;
    int src = n; float4 w4 = make_float4(0.f,0.f,0.f,0.f);
    if (e < cnt){
      src = csr_src[p0+e];
      float4 av = *(const float4*)(als + src*4);
      w4.x = expf(leaky(av.x + aldn4.x));
      w4.y = expf(leaky(av.y + aldn4.y));
      w4.z = expf(leaky(av.z + aldn4.z));
      w4.w = expf(leaky(av.w + aldn4.w));
    }
    s_src[lane] = src;                 // pad: src=n (valid), w=0
    *(float4*)&s_w[lane][0] = w4;
    int ce = min(64, cnt - c);
    int cp = (ce+7)&~7;                // step 8: 4 uint4 loads in flight
    for (int i=0;i<cp;i+=8){
      int src0 = s_src[i+r],   src1 = s_src[i+2+r];
      int src2 = s_src[i+4+r], src3 = s_src[i+6+r];
      float w0 = s_w[i+r][head],   w1 = s_w[i+2+r][head];
      float w2 = s_w[i+4+r][head], w3 = s_w[i+6+r][head];
      uint4 h0 = *(const uint4*)(h + (size_t)src0*256 + f*8);
      uint4 h1 = *(const uint4*)(h + (size_t)src1*256 + f*8);
      uint4 h2 = *(const uint4*)(h + (size_t)src2*256 + f*8);
      uint4 h3 = *(const uint4*)(h + (size_t)src3*256 + f*8);
      ssum += (w0 + w1) + (w2 + w3);
      acc[0]=fmaf(bflo(h0.x),w0,acc[0]); acc[1]=fmaf(bfhi(h0.x),w0,acc[1]);
      acc[2]=fmaf(bflo(h0.y),w0,acc[2]); acc[3]=fmaf(bfhi(h0.y),w0,acc[3]);
      acc[4]=fmaf(bflo(h0.z),w0,acc[4]); acc[5]=fmaf(bfhi(h0.z),w0,acc[5]);
      acc[6]=fmaf(bflo(h0.w),w0,acc[6]); acc[7]=fmaf(bfhi(h0.w),w0,acc[7]);
      acc[0]=fmaf(bflo(h1.x),w1,acc[0]); acc[1]=fmaf(bfhi(h1.x),w1,acc[1]);
      acc[2]=fmaf(bflo(h1.y),w1,acc[2]); acc[3]=fmaf(bfhi(h1.y),w1,acc[3]);
      acc[4]=fmaf(bflo(h1.z),w1,acc[4]); acc[5]=fmaf(bfhi(h1.z),w1,acc[5]);
      acc[6]=fmaf(bflo(h1.w),w1,acc[6]); acc[7]=fmaf(bfhi(h1.w),w1,acc[7]);
      acc[0]=fmaf(bflo(h2.x),w2,acc[0]); acc[1]=fmaf(bfhi(h2.x),w2,acc[1]);
      acc[2]=fmaf(bflo(h2.y),w2,acc[2]); acc[3]=fmaf(bfhi(h2.y),w2,acc[3]);
      acc[4]=fmaf(bflo(h2.z),w2,acc[4]); acc[5]=fmaf(bfhi(h2.z),w2,acc[5]);
      acc[6]=fmaf(bflo(h2.w),w2,acc[6]); acc[7]=fmaf(bfhi(h2.w),w2,acc[7]);
      acc[0]=fmaf(bflo(h3.x),w3,acc[0]); acc[1]=fmaf(bfhi(h3.x),w3,acc[1]);
      acc[2]=fmaf(bflo(h3.y),w3,acc[2]); acc[3]=fmaf(bfhi(h3.y),w3,acc[3]);
      acc[4]=fmaf(bflo(h3.z),w3,acc[4]); acc[5]=fmaf(bfhi(h3.z),w3,acc[5]);
      acc[6]=fmaf(bflo(h3.w),w3,acc[6]); acc[7]=fmaf(bfhi(h3.w),w3,acc[7]);
    }
  }
  #pragma unroll
  for (int j=0;j<8;++j) acc[j] += __shfl_xor(acc[j], 32);
  ssum += __shfl_xor(ssum, 32);
  if (r==0){
    float inv = 1.f/(ssum + 1e-16f);
    float4 b0 = *(const float4*)(bias + f*8);
    float4 b1 = *(const float4*)(bias + f*8 + 4);
    float rv[8];
    rv[0]=acc[0]*inv+b0.x; rv[1]=acc[1]*inv+b0.y; rv[2]=acc[2]*inv+b0.z; rv[3]=acc[3]*inv+b0.w;
    rv[4]=acc[4]*inv+b1.x; rv[5]=acc[5]*inv+b1.y; rv[6]=acc[6]*inv+b1.z; rv[7]=acc[7]*inv+b1.w;
    union{ bf16 b[8]; uint4 u; } pk;
    #pragma unroll
    for (int j=0;j<8;++j){
      float v = rv[j];
      if (ELU) v = (v>0.f)?v:expm1f(v);
      pk.b[j] = __float2bfloat16(v);
    }
    *(uint4*)(out + (size_t)n*256 + f*8) = pk.u;
  }
}

// ------- single-pass scatter-softmax + aggregate, H=1 (1 wave/node) -------
// lane = parity r (lane>>4) x feature-quad f (lane&15); uint2 loads => 4 rows
// per wave-instruction; combine via shfl_xor(16)+shfl_xor(32).
__global__ __launch_bounds__(64) void aggregate1_kernel(const bf16* __restrict__ h,
        const float* __restrict__ als, const float* __restrict__ ald,
        const int* __restrict__ off, const int* __restrict__ deg,
        const int* __restrict__ csr_src,
        const float* __restrict__ bias, bf16* __restrict__ out){
  __shared__ int   s_src[64];
  __shared__ float s_w[64];
  const int n = blockIdx.x, lane = threadIdx.x;
  const int r = lane>>4;            // edge parity (0..3)
  const int f = lane&15;            // feature quad: features f*4..f*4+3
  const int p0 = off[n], cnt = deg[n]+1;
  const float aldn = ald[n];
  float ssum = 0.f;
  float acc[4] = {};
  for (int c=0; c<cnt; c+=64){
    int e = c + lane;
    int src = n; float wv = 0.f;
    if (e < cnt){
      src = csr_src[p0+e];
      wv = expf(leaky(als[src] + aldn));
    }
    s_src[lane] = src; s_w[lane] = wv;
    int ce = min(64, cnt - c);
    int cp = (ce+7)&~7;              // step 8: 2 uint2 loads in flight
    for (int i=0;i<cp;i+=8){
      int src0 = s_src[i+r], src1 = s_src[i+4+r];
      float w0 = s_w[i+r],   w1 = s_w[i+4+r];
      uint2 h0 = *(const uint2*)(h + (size_t)src0*64 + f*4);
      uint2 h1 = *(const uint2*)(h + (size_t)src1*64 + f*4);
      ssum += w0 + w1;
      acc[0]=fmaf(bflo(h0.x),w0,acc[0]); acc[1]=fmaf(bfhi(h0.x),w0,acc[1]);
      acc[2]=fmaf(bflo(h0.y),w0,acc[2]); acc[3]=fmaf(bfhi(h0.y),w0,acc[3]);
      acc[0]=fmaf(bflo(h1.x),w1,acc[0]); acc[1]=fmaf(bfhi(h1.x),w1,acc[1]);
      acc[2]=fmaf(bflo(h1.y),w1,acc[2]); acc[3]=fmaf(bfhi(h1.y),w1,acc[3]);
    }
  }
  #pragma unroll
  for (int j=0;j<4;++j){
    acc[j] += __shfl_xor(acc[j], 16);
    acc[j] += __shfl_xor(acc[j], 32);
  }
  ssum += __shfl_xor(ssum, 16);
  ssum += __shfl_xor(ssum, 32);
  if (r==0){
    float inv = 1.f/(ssum + 1e-16f);
    union{ bf16 b[4]; uint2 u; } pk;
    #pragma unroll
    for (int j=0;j<4;++j) pk.b[j] = __float2bfloat16(acc[j]*inv + bias[f*4+j]);
    *(uint2*)(out + (size_t)n*64 + f*4) = pk.u;
  }
}

// ---------------- chunked pooling (batch sorted) ----------------
__global__ __launch_bounds__(64) void pool_kernel(const bf16* __restrict__ h3,
        const int* __restrict__ batch, float* __restrict__ psum, float* __restrict__ pcnt,
        int N, int chunk){
  int n0 = blockIdx.x*chunk;
  if (n0 >= N) return;
  int n1 = min(N, n0+chunk);
  int t = threadIdx.x;
  int gcur = batch[n0];
  float acc = 0.f, cnt = 0.f;
  for (int n=n0; n<n1; ++n){
    int g = batch[n];
    if (g != gcur){
      atomicAdd(&psum[gcur*64+t], acc);
      if (t==0) atomicAdd(&pcnt[gcur], cnt);
      acc = 0.f; cnt = 0.f; gcur = g;
    }
    acc += bf2f(h3[(size_t)n*64+t]);
    cnt += 1.f;
  }
  atomicAdd(&psum[gcur*64+t], acc);
  if (t==0) atomicAdd(&pcnt[gcur], cnt);
}

__global__ __launch_bounds__(64) void head_kernel(const float* __restrict__ psum,
        const float* __restrict__ pcnt,
        const float* __restrict__ Wmu, const float* __restrict__ bmu,
        const float* __restrict__ Wlv, const float* __restrict__ blv,
        float* __restrict__ out){
  int g = blockIdx.x, t = threadIdx.x;
  __shared__ float p[64];
  float cnt = fmaxf(pcnt[g], 1.0f);
  p[t] = psum[g*64+t] / cnt;
  __syncthreads();
  float mu = bmu[t], lv = blv[t];
  for (int k=0;k<64;++k){
    float pk = p[k];
    mu = fmaf(pk, Wmu[(size_t)k*64+t], mu);
    lv = fmaf(pk, Wlv[(size_t)k*64+t], lv);
  }
  int i = g*64 + t;
  unsigned x0 = 0u, x1 = (unsigned)i;
  threefry2x32(0u, 42u, x0, x1);
  unsigned bits = x0 ^ x1;
  float f = __uint_as_float((bits>>9) | 0x3F800000u) - 1.0f;   // [0,1)
  const float lo = __uint_as_float(0xBF7FFFFFu);               // -(1-2^-24)
  float u = fmaxf(lo, f*2.0f + lo);
  float eps = 1.41421356f * erfinv_approx(u);
  float z = mu + eps * expf(0.5f*lv);
  out[i]        = mu;
  out[4096 + i] = lv;
  out[8192 + i] = z;
}

// ---------------- launch ----------------
extern "C" void kernel_launch(void* const* d_in, const int* in_sizes, int n_in,
                              void* d_out, int out_size, void* d_ws, size_t ws_size,
                              hipStream_t stream){
  const float* x    = (const float*)d_in[0];
  const int*   ei   = (const int*)d_in[1];
  const int*   batch= (const int*)d_in[2];
  const float* W1   = (const float*)d_in[3];
  const float* a1s  = (const float*)d_in[4];
  const float* a1d  = (const float*)d_in[5];
  const float* b1   = (const float*)d_in[6];
  const float* W2   = (const float*)d_in[7];
  const float* a2s  = (const float*)d_in[8];
  const float* a2d  = (const float*)d_in[9];
  const float* b2   = (const float*)d_in[10];
  const float* W3   = (const float*)d_in[11];
  const float* a3s  = (const float*)d_in[12];
  const float* a3d  = (const float*)d_in[13];
  const float* b3   = (const float*)d_in[14];
  const float* Wmu  = (const float*)d_in[15];
  const float* bmu  = (const float*)d_in[16];
  const float* Wlv  = (const float*)d_in[17];
  const float* blv  = (const float*)d_in[18];
  float* out = (float*)d_out;

  const int N = N_NODES, E = N_EDGES;
  const int ET = E + N;

  char* ws = (char*)d_ws;
  size_t o = 0;
  auto alloc = [&](size_t bytes)->void*{
    void* p = ws + o; o += (bytes + 255) & ~(size_t)255; return p;
  };
  bf16*  hA      = (bf16*) alloc((size_t)N*256*2);   // 25.6 MB
  bf16*  hB      = (bf16*) alloc((size_t)N*256*2);   // 25.6 MB
  float* als     = (float*)alloc((size_t)N*4*4);
  float* ald     = (float*)alloc((size_t)N*4*4);
  int*   deg     = (int*)  alloc((size_t)(N+1)*4);   // deg[N] = total
  int*   total   = deg + N;
  int*   off     = (int*)  alloc((size_t)N*4);
  int*   cursor  = (int*)  alloc((size_t)N*4);
  int*   csr_src = (int*)  alloc((size_t)ET*4);
  short* Wt1     = (short*)alloc(256*256*2);
  short* Wt2     = (short*)alloc(256*256*2);
  short* Wt3     = (short*)alloc(64*256*2);
  float* psum    = (float*)alloc(64*64*4 + 64*4);    // psum + pcnt contiguous
  float* pcnt    = psum + 64*64;
  (void)ws_size; (void)n_in; (void)in_sizes; (void)out_size;

  const int TB = 256;
  const int egrid = (ET + TB - 1)/TB;

  // W transposes (bf16 [n][k]) — single launch
  wt_all_kernel<<<dim3(8,8,3), 256, 0, stream>>>(W1, W2, W3, Wt1, Wt2, Wt3);

  // scan-free CSR by destination (rebuilt every call; ws re-poisoned per launch)
  hipMemsetAsync(deg, 0, (size_t)(N+1)*4, stream);
  count_kernel<<<(E+TB-1)/TB, TB, 0, stream>>>(ei, deg, E);
  assign_kernel<<<(N+TB-1)/TB, TB, 0, stream>>>(deg, off, cursor, total, N);
  fill_kernel<<<egrid, TB, 0, stream>>>(ei, cursor, csr_src, E, N);

  // ---- layer 1: x(f32) @ W1, H=4, ELU ----
  gemm_mfma_kernel<256,false><<<(N+63)/64, 256, 0, stream>>>(x, Wt1, hB, a1s, a1d, als, ald, N);
  aggregate4_kernel<true><<<N, 64, 0, stream>>>(hB, als, ald, off, deg, csr_src, b1, hA);

  // ---- layer 2: hA(bf16) @ W2, H=4, ELU ----
  gemm_mfma_kernel<256,true><<<(N+63)/64, 256, 0, stream>>>(hA, Wt2, hB, a2s, a2d, als, ald, N);
  aggregate4_kernel<true><<<N, 64, 0, stream>>>(hB, als, ald, off, deg, csr_src, b2, hA);

  // ---- layer 3: hA(bf16) @ W3, H=1, no ELU ----
  gemm_mfma_kernel<64,true><<<(N+255)/256, 256, 0, stream>>>(hA, Wt3, hB, a3s, a3d, als, ald, N);
  aggregate1_kernel<<<N, 64, 0, stream>>>(hB, als, ald, off, deg, csr_src, b3, hA);

  // ---- pool + VAE head ----
  hipMemsetAsync(psum, 0, 64*64*4 + 64*4, stream);
  const int PBLK = 512;
  const int chunk = (N + PBLK - 1)/PBLK;
  pool_kernel<<<PBLK, 64, 0, stream>>>(hA, batch, psum, pcnt, N, chunk);
  head_kernel<<<64, 64, 0, stream>>>(psum, pcnt, Wmu, bmu, Wlv, blv, out);
}

// Round 10
// 460.595 us; speedup vs baseline: 4.9305x; 1.0862x over previous
//
#include <hip/hip_runtime.h>
#include <hip/hip_bf16.h>
#include <cstdint>
#include <math.h>

// PathwayGraphEncoder: 3-layer GAT (+self-loops, scatter-softmax) -> mean pool
// -> VAE head with JAX partitionable-threefry eps.
// R10: fp8(e4m3) gather payload. hB is consumed ONLY by the aggregate gather,
// so gemm<256> epilogue stores fp8 directly from f32 accs (512->256 B/row);
// agg4 decodes via cvt_pk_f32_fp8, 4 rows per wave-load. R9 showed the gather
// is L2-miss-byte-bound at ~3.7 TB/s => halve the bytes.

#define N_NODES 50000
#define N_EDGES 800000
#define NEG_SLOPE 0.2f

typedef __hip_bfloat16 bf16;
typedef short short8 __attribute__((ext_vector_type(8)));
typedef float floatx4 __attribute__((ext_vector_type(4)));
typedef float floatx2 __attribute__((ext_vector_type(2)));

__device__ __forceinline__ float bf2f(bf16 v){ return __bfloat162float(v); }
__device__ __forceinline__ float bflo(unsigned u){ union{unsigned u; float f;} c; c.u = u<<16; return c.f; }
__device__ __forceinline__ float bfhi(unsigned u){ union{unsigned u; float f;} c; c.u = u & 0xFFFF0000u; return c.f; }
__device__ __forceinline__ float leaky(float v){ return v>0.f ? v : NEG_SLOPE*v; }
__device__ __forceinline__ unsigned short f2bu(float f){
  union{ bf16 b; unsigned short u; } c; c.b = __float2bfloat16(f); return c.u;
}
__device__ __forceinline__ unsigned char f2fp8(float v){
  int p = __builtin_amdgcn_cvt_pk_fp8_f32(v, v, 0, false);
  return (unsigned char)(p & 0xff);
}
__device__ __forceinline__ void acc_fp8x4(float* acc, unsigned wrd, float wgt){
  floatx2 lo = __builtin_amdgcn_cvt_pk_f32_fp8((int)wrd, false);
  floatx2 hi = __builtin_amdgcn_cvt_pk_f32_fp8((int)wrd, true);
  acc[0] = fmaf(lo[0], wgt, acc[0]);
  acc[1] = fmaf(lo[1], wgt, acc[1]);
  acc[2] = fmaf(hi[0], wgt, acc[2]);
  acc[3] = fmaf(hi[1], wgt, acc[3]);
}

// ---------------- threefry2x32 (JAX-compatible) ----------------
__device__ __forceinline__ void tf_round(unsigned& x0, unsigned& x1, int r){
  x0 += x1; x1 = (x1<<r)|(x1>>(32-r)); x1 ^= x0;
}
__device__ __forceinline__ void threefry2x32(unsigned k0, unsigned k1, unsigned& x0, unsigned& x1){
  unsigned ks2 = k0 ^ k1 ^ 0x1BD11BDAu;
  x0 += k0; x1 += k1;
  tf_round(x0,x1,13); tf_round(x0,x1,15); tf_round(x0,x1,26); tf_round(x0,x1,6);
  x0 += k1; x1 += ks2 + 1u;
  tf_round(x0,x1,17); tf_round(x0,x1,29); tf_round(x0,x1,16); tf_round(x0,x1,24);
  x0 += ks2; x1 += k0 + 2u;
  tf_round(x0,x1,13); tf_round(x0,x1,15); tf_round(x0,x1,26); tf_round(x0,x1,6);
  x0 += k0; x1 += k1 + 3u;
  tf_round(x0,x1,17); tf_round(x0,x1,29); tf_round(x0,x1,16); tf_round(x0,x1,24);
  x0 += k1; x1 += ks2 + 4u;
  tf_round(x0,x1,13); tf_round(x0,x1,15); tf_round(x0,x1,26); tf_round(x0,x1,6);
  x0 += ks2; x1 += k0 + 5u;
}

// Giles single-precision erfinv (XLA ErfInv32 coefficients)
__device__ __forceinline__ float erfinv_approx(float x){
  float w = -log1pf(-x*x);
  float p;
  if (w < 5.0f){
    w = w - 2.5f;
    p = 2.81022636e-08f;
    p = fmaf(p,w,3.43273939e-07f);
    p = fmaf(p,w,-3.5233877e-06f);
    p = fmaf(p,w,-4.39150654e-06f);
    p = fmaf(p,w,0.00021858087f);
    p = fmaf(p,w,-0.00125372503f);
    p = fmaf(p,w,-0.00417768164f);
    p = fmaf(p,w,0.246640727f);
    p = fmaf(p,w,1.50140941f);
  } else {
    w = sqrtf(w) - 3.0f;
    p = -0.000200214257f;
    p = fmaf(p,w,0.000100950558f);
    p = fmaf(p,w,0.00134934322f);
    p = fmaf(p,w,-0.00367342844f);
    p = fmaf(p,w,0.00573950773f);
    p = fmaf(p,w,-0.0076224613f);
    p = fmaf(p,w,0.00943887047f);
    p = fmaf(p,w,1.00167406f);
    p = fmaf(p,w,2.83297682f);
  }
  return p*x;
}

// ------- W transposes (all 3 in one launch): Wt[n][k] bf16 from W[k][n] f32 -------
__global__ __launch_bounds__(256) void wt_all_kernel(
        const float* __restrict__ W1, const float* __restrict__ W2,
        const float* __restrict__ W3, short* __restrict__ Wt1,
        short* __restrict__ Wt2, short* __restrict__ Wt3){
  const float* W; short* Wt; int Nn;
  if (blockIdx.z == 0){ W = W1; Wt = Wt1; Nn = 256; }
  else if (blockIdx.z == 1){ W = W2; Wt = Wt2; Nn = 256; }
  else { W = W3; Wt = Wt3; Nn = 64; }
  const int n0 = blockIdx.x*32, k0 = blockIdx.y*32;
  if (n0 >= Nn) return;
  __shared__ float tile[32][33];
  const int tx = threadIdx.x & 31, ty = threadIdx.x >> 5;   // 32 x 8
  #pragma unroll
  for (int i=0;i<4;++i)
    tile[ty+8*i][tx] = W[(size_t)(k0+ty+8*i)*Nn + n0 + tx];
  __syncthreads();
  #pragma unroll
  for (int i=0;i<4;++i)
    Wt[(size_t)(n0+ty+8*i)*256 + k0 + tx] = (short)f2bu(tile[tx][ty+8*i]);
}

// ---------------- MFMA GEMM + fused attention coefficients ----------------
// OUT=256: out is fp8 e4m3 (gather payload). OUT=64: out is bf16.
template<int OUT, bool INBF>
__global__ __launch_bounds__(256) void gemm_mfma_kernel(const void* __restrict__ inp,
        const short* __restrict__ Wt, void* __restrict__ outv,
        const float* __restrict__ a_s, const float* __restrict__ a_d,
        float* __restrict__ als, float* __restrict__ ald, int N){
  constexpr int M_BLK = (OUT==256) ? 64 : 256;
  constexpr int H = (OUT==256) ? 4 : 1;
  __shared__ short As[M_BLK*48];
  __shared__ short Bs[OUT*48];
  const int t = threadIdx.x;
  const int w = t>>6, lane = t&63;
  const int lm = lane&15, g = lane>>4;
  const int m0 = blockIdx.x * M_BLK;
  const int m_off = (OUT==256) ? 0 : w*64;
  const int n0    = (OUT==256) ? w*64 : 0;

  floatx4 acc[4][4] = {};

  for (int kk=0; kk<8; ++kk){
    const int k0 = kk*32;
    __syncthreads();
    for (int a = t; a < M_BLK*4; a += 256){
      int r = a>>2, c = a&3;
      int gr = m0 + r;
      uint4 v = make_uint4(0u,0u,0u,0u);
      if (gr < N){
        if constexpr (INBF){
          v = *(const uint4*)((const bf16*)inp + (size_t)gr*256 + k0 + c*8);
        } else {
          const float* p = (const float*)inp + (size_t)gr*256 + k0 + c*8;
          float4 f0 = *(const float4*)p;
          float4 f1 = *(const float4*)(p+4);
          v.x = (unsigned)f2bu(f0.x) | ((unsigned)f2bu(f0.y)<<16);
          v.y = (unsigned)f2bu(f0.z) | ((unsigned)f2bu(f0.w)<<16);
          v.z = (unsigned)f2bu(f1.x) | ((unsigned)f2bu(f1.y)<<16);
          v.w = (unsigned)f2bu(f1.z) | ((unsigned)f2bu(f1.w)<<16);
        }
      }
      *(uint4*)&As[r*48 + c*8] = v;
    }
    for (int a = t; a < OUT*4; a += 256){
      int r = a>>2, c = a&3;
      uint4 v = *(const uint4*)(Wt + (size_t)r*256 + k0 + c*8);
      *(uint4*)&Bs[r*48 + c*8] = v;
    }
    __syncthreads();
    short8 af[4], bfr[4];
    #pragma unroll
    for (int mt=0;mt<4;++mt)
      af[mt] = *(const short8*)&As[(m_off + mt*16 + lm)*48 + g*8];
    #pragma unroll
    for (int nt=0;nt<4;++nt)
      bfr[nt] = *(const short8*)&Bs[(n0 + nt*16 + lm)*48 + g*8];
    #pragma unroll
    for (int mt=0;mt<4;++mt)
      #pragma unroll
      for (int nt=0;nt<4;++nt)
        acc[mt][nt] = __builtin_amdgcn_mfma_f32_16x16x32_bf16(af[mt], bfr[nt], acc[mt][nt], 0, 0, 0);
  }

  float asv[4], adv[4];
  #pragma unroll
  for (int nt=0;nt<4;++nt){
    asv[nt] = a_s[n0 + nt*16 + lm];
    adv[nt] = a_d[n0 + nt*16 + lm];
  }
  const int head = (OUT==256) ? w : 0;
  #pragma unroll
  for (int mt=0;mt<4;++mt){
    #pragma unroll
    for (int reg=0;reg<4;++reg){
      int gr = m0 + m_off + mt*16 + g*4 + reg;
      bool valid = gr < N;
      float ps = 0.f, pd = 0.f;
      #pragma unroll
      for (int nt=0;nt<4;++nt){
        float v = acc[mt][nt][reg];
        if (valid){
          if constexpr (OUT==256){
            ((unsigned char*)outv)[(size_t)gr*256 + n0 + nt*16 + lm] = f2fp8(v);
          } else {
            ((bf16*)outv)[(size_t)gr*OUT + n0 + nt*16 + lm] = __float2bfloat16(v);
          }
        }
        ps = fmaf(v, asv[nt], ps);
        pd = fmaf(v, adv[nt], pd);
      }
      #pragma unroll
      for (int o=1;o<16;o<<=1){ ps += __shfl_xor(ps,o); pd += __shfl_xor(pd,o); }
      if (lm==0 && valid){
        als[gr*H + head] = ps;
        ald[gr*H + head] = pd;
      }
    }
  }
}

// ---------------- scan-free CSR build (by destination, + self-loops) ----------------
__global__ void count_kernel(const int* __restrict__ ei, int* __restrict__ deg, int E){
  int e = blockIdx.x*blockDim.x+threadIdx.x; if (e<E) atomicAdd(&deg[ei[E+e]], 1);
}
__global__ void assign_kernel(const int* __restrict__ deg, int* __restrict__ off,
        int* __restrict__ cursor, int* __restrict__ total, int N){
  int i = blockIdx.x*blockDim.x+threadIdx.x;
  if (i<N){
    int d = deg[i] + 1;                       // +1 self-loop
    int start = atomicAdd(total, d);          // unordered segments: fine
    off[i] = start; cursor[i] = start;
  }
}
__global__ void fill_kernel(const int* __restrict__ ei, int* __restrict__ cursor,
        int* __restrict__ csr_src, int E, int N){
  int e = blockIdx.x*blockDim.x+threadIdx.x;
  if (e >= E+N) return;
  int s_ = (e < E) ? ei[e]   : e-E;
  int d_ = (e < E) ? ei[E+e] : e-E;
  int p = atomicAdd(&cursor[d_], 1);
  csr_src[p] = s_;
}

// ------- single-pass scatter-softmax + aggregate, H=4, fp8 h (1 wave/node) -------
// lane = parity r (lane>>4, 4 edges) x feature-16 f (lane&15); uint4 = 16 fp8
// => 4 rows per wave-instruction; combine via shfl_xor(16)+shfl_xor(32).
template<bool ELU>
__global__ __launch_bounds__(64) void aggregate4_kernel(const unsigned char* __restrict__ h8,
        const float* __restrict__ als, const float* __restrict__ ald,
        const int* __restrict__ off, const int* __restrict__ deg,
        const int* __restrict__ csr_src,
        const float* __restrict__ bias, bf16* __restrict__ out){
  __shared__ int   s_src[64];
  __shared__ float s_w[64][4];
  const int n = blockIdx.x, lane = threadIdx.x;
  const int r = lane>>4;            // edge parity (0..3)
  const int f = lane&15;            // features f*16..f*16+15
  const int head = f>>2;
  const int p0 = off[n], cnt = deg[n]+1;
  const float4 aldn4 = *(const float4*)(ald + n*4);
  float ssum = 0.f;
  float acc[16] = {};
  for (int c=0; c<cnt; c+=64){
    int e = c + lane;
    int src = n; float4 w4 = make_float4(0.f,0.f,0.f,0.f);
    if (e < cnt){
      src = csr_src[p0+e];
      float4 av = *(const float4*)(als + src*4);
      w4.x = expf(leaky(av.x + aldn4.x));
      w4.y = expf(leaky(av.y + aldn4.y));
      w4.z = expf(leaky(av.z + aldn4.z));
      w4.w = expf(leaky(av.w + aldn4.w));
    }
    s_src[lane] = src;                 // pad: src=n (valid addr), w=0
    *(float4*)&s_w[lane][0] = w4;
    int ce = min(64, cnt - c);
    int cp = (ce+7)&~7;                // step 8: 2 uint4 loads in flight
    for (int i=0;i<cp;i+=8){
      int src0 = s_src[i+r], src1 = s_src[i+4+r];
      float w0 = s_w[i+r][head], w1 = s_w[i+4+r][head];
      uint4 h0 = *(const uint4*)(h8 + (size_t)src0*256 + f*16);
      uint4 h1 = *(const uint4*)(h8 + (size_t)src1*256 + f*16);
      ssum += w0 + w1;
      acc_fp8x4(acc+0,  h0.x, w0); acc_fp8x4(acc+4,  h0.y, w0);
      acc_fp8x4(acc+8,  h0.z, w0); acc_fp8x4(acc+12, h0.w, w0);
      acc_fp8x4(acc+0,  h1.x, w1); acc_fp8x4(acc+4,  h1.y, w1);
      acc_fp8x4(acc+8,  h1.z, w1); acc_fp8x4(acc+12, h1.w, w1);
    }
  }
  #pragma unroll
  for (int j=0;j<16;++j){
    acc[j] += __shfl_xor(acc[j], 16);
    acc[j] += __shfl_xor(acc[j], 32);
  }
  ssum += __shfl_xor(ssum, 16);
  ssum += __shfl_xor(ssum, 32);
  if (r==0){
    float inv = 1.f/(ssum + 1e-16f);
    #pragma unroll
    for (int half=0; half<2; ++half){
      float4 b0 = *(const float4*)(bias + f*16 + half*8);
      float4 b1 = *(const float4*)(bias + f*16 + half*8 + 4);
      float rv[8];
      rv[0]=acc[half*8+0]*inv+b0.x; rv[1]=acc[half*8+1]*inv+b0.y;
      rv[2]=acc[half*8+2]*inv+b0.z; rv[3]=acc[half*8+3]*inv+b0.w;
      rv[4]=acc[half*8+4]*inv+b1.x; rv[5]=acc[half*8+5]*inv+b1.y;
      rv[6]=acc[half*8+6]*inv+b1.z; rv[7]=acc[half*8+7]*inv+b1.w;
      union{ bf16 b[8]; uint4 u; } pk;
      #pragma unroll
      for (int j=0;j<8;++j){
        float v = rv[j];
        if (ELU) v = (v>0.f)?v:expm1f(v);
        pk.b[j] = __float2bfloat16(v);
      }
      *(uint4*)(out + (size_t)n*256 + f*16 + half*8) = pk.u;
    }
  }
}

// ------- single-pass scatter-softmax + aggregate, H=1, bf16 h (1 wave/node) -------
__global__ __launch_bounds__(64) void aggregate1_kernel(const bf16* __restrict__ h,
        const float* __restrict__ als, const float* __restrict__ ald,
        const int* __restrict__ off, const int* __restrict__ deg,
        const int* __restrict__ csr_src,
        const float* __restrict__ bias, bf16* __restrict__ out){
  __shared__ int   s_src[64];
  __shared__ float s_w[64];
  const int n = blockIdx.x, lane = threadIdx.x;
  const int r = lane>>4;            // edge parity (0..3)
  const int f = lane&15;            // feature quad: features f*4..f*4+3
  const int p0 = off[n], cnt = deg[n]+1;
  const float aldn = ald[n];
  float ssum = 0.f;
  float acc[4] = {};
  for (int c=0; c<cnt; c+=64){
    int e = c + lane;
    int src = n; float wv = 0.f;
    if (e < cnt){
      src = csr_src[p0+e];
      wv = expf(leaky(als[src] + aldn));
    }
    s_src[lane] = src; s_w[lane] = wv;
    int ce = min(64, cnt - c);
    int cp = (ce+7)&~7;              // step 8: 2 uint2 loads in flight
    for (int i=0;i<cp;i+=8){
      int src0 = s_src[i+r], src1 = s_src[i+4+r];
      float w0 = s_w[i+r],   w1 = s_w[i+4+r];
      uint2 h0 = *(const uint2*)(h + (size_t)src0*64 + f*4);
      uint2 h1 = *(const uint2*)(h + (size_t)src1*64 + f*4);
      ssum += w0 + w1;
      acc[0]=fmaf(bflo(h0.x),w0,acc[0]); acc[1]=fmaf(bfhi(h0.x),w0,acc[1]);
      acc[2]=fmaf(bflo(h0.y),w0,acc[2]); acc[3]=fmaf(bfhi(h0.y),w0,acc[3]);
      acc[0]=fmaf(bflo(h1.x),w1,acc[0]); acc[1]=fmaf(bfhi(h1.x),w1,acc[1]);
      acc[2]=fmaf(bflo(h1.y),w1,acc[2]); acc[3]=fmaf(bfhi(h1.y),w1,acc[3]);
    }
  }
  #pragma unroll
  for (int j=0;j<4;++j){
    acc[j] += __shfl_xor(acc[j], 16);
    acc[j] += __shfl_xor(acc[j], 32);
  }
  ssum += __shfl_xor(ssum, 16);
  ssum += __shfl_xor(ssum, 32);
  if (r==0){
    float inv = 1.f/(ssum + 1e-16f);
    union{ bf16 b[4]; uint2 u; } pk;
    #pragma unroll
    for (int j=0;j<4;++j) pk.b[j] = __float2bfloat16(acc[j]*inv + bias[f*4+j]);
    *(uint2*)(out + (size_t)n*64 + f*4) = pk.u;
  }
}

// ---------------- chunked pooling (batch sorted) ----------------
__global__ __launch_bounds__(64) void pool_kernel(const bf16* __restrict__ h3,
        const int* __restrict__ batch, float* __restrict__ psum, float* __restrict__ pcnt,
        int N, int chunk){
  int n0 = blockIdx.x*chunk;
  if (n0 >= N) return;
  int n1 = min(N, n0+chunk);
  int t = threadIdx.x;
  int gcur = batch[n0];
  float acc = 0.f, cnt = 0.f;
  for (int n=n0; n<n1; ++n){
    int g = batch[n];
    if (g != gcur){
      atomicAdd(&psum[gcur*64+t], acc);
      if (t==0) atomicAdd(&pcnt[gcur], cnt);
      acc = 0.f; cnt = 0.f; gcur = g;
    }
    acc += bf2f(h3[(size_t)n*64+t]);
    cnt += 1.f;
  }
  atomicAdd(&psum[gcur*64+t], acc);
  if (t==0) atomicAdd(&pcnt[gcur], cnt);
}

__global__ __launch_bounds__(64) void head_kernel(const float* __restrict__ psum,
        const float* __restrict__ pcnt,
        const float* __restrict__ Wmu, const float* __restrict__ bmu,
        const float* __restrict__ Wlv, const float* __restrict__ blv,
        float* __restrict__ out){
  int g = blockIdx.x, t = threadIdx.x;
  __shared__ float p[64];
  float cnt = fmaxf(pcnt[g], 1.0f);
  p[t] = psum[g*64+t] / cnt;
  __syncthreads();
  float mu = bmu[t], lv = blv[t];
  for (int k=0;k<64;++k){
    float pk = p[k];
    mu = fmaf(pk, Wmu[(size_t)k*64+t], mu);
    lv = fmaf(pk, Wlv[(size_t)k*64+t], lv);
  }
  int i = g*64 + t;
  unsigned x0 = 0u, x1 = (unsigned)i;
  threefry2x32(0u, 42u, x0, x1);
  unsigned bits = x0 ^ x1;
  float f = __uint_as_float((bits>>9) | 0x3F800000u) - 1.0f;   // [0,1)
  const float lo = __uint_as_float(0xBF7FFFFFu);               // -(1-2^-24)
  float u = fmaxf(lo, f*2.0f + lo);
  float eps = 1.41421356f * erfinv_approx(u);
  float z = mu + eps * expf(0.5f*lv);
  out[i]        = mu;
  out[4096 + i] = lv;
  out[8192 + i] = z;
}

// ---------------- launch ----------------
extern "C" void kernel_launch(void* const* d_in, const int* in_sizes, int n_in,
                              void* d_out, int out_size, void* d_ws, size_t ws_size,
                              hipStream_t stream){
  const float* x    = (const float*)d_in[0];
  const int*   ei   = (const int*)d_in[1];
  const int*   batch= (const int*)d_in[2];
  const float* W1   = (const float*)d_in[3];
  const float* a1s  = (const float*)d_in[4];
  const float* a1d  = (const float*)d_in[5];
  const float* b1   = (const float*)d_in[6];
  const float* W2   = (const float*)d_in[7];
  const float* a2s  = (const float*)d_in[8];
  const float* a2d  = (const float*)d_in[9];
  const float* b2   = (const float*)d_in[10];
  const float* W3   = (const float*)d_in[11];
  const float* a3s  = (const float*)d_in[12];
  const float* a3d  = (const float*)d_in[13];
  const float* b3   = (const float*)d_in[14];
  const float* Wmu  = (const float*)d_in[15];
  const float* bmu  = (const float*)d_in[16];
  const float* Wlv  = (const float*)d_in[17];
  const float* blv  = (const float*)d_in[18];
  float* out = (float*)d_out;

  const int N = N_NODES, E = N_EDGES;
  const int ET = E + N;

  char* ws = (char*)d_ws;
  size_t o = 0;
  auto alloc = [&](size_t bytes)->void*{
    void* p = ws + o; o += (bytes + 255) & ~(size_t)255; return p;
  };
  bf16*  hA      = (bf16*) alloc((size_t)N*256*2);       // 25.6 MB (agg out / gemm in)
  unsigned char* hB8 = (unsigned char*)alloc((size_t)N*256); // 12.8 MB fp8 gather payload
  bf16*  h3      = (bf16*) alloc((size_t)N*64*2);        // 6.4 MB (layer3 gemm out)
  float* als     = (float*)alloc((size_t)N*4*4);
  float* ald     = (float*)alloc((size_t)N*4*4);
  int*   deg     = (int*)  alloc((size_t)(N+1)*4);       // deg[N] = total
  int*   total   = deg + N;
  int*   off     = (int*)  alloc((size_t)N*4);
  int*   cursor  = (int*)  alloc((size_t)N*4);
  int*   csr_src = (int*)  alloc((size_t)ET*4);
  short* Wt1     = (short*)alloc(256*256*2);
  short* Wt2     = (short*)alloc(256*256*2);
  short* Wt3     = (short*)alloc(64*256*2);
  float* psum    = (float*)alloc(64*64*4 + 64*4);        // psum + pcnt contiguous
  float* pcnt    = psum + 64*64;
  (void)ws_size; (void)n_in; (void)in_sizes; (void)out_size;

  const int TB = 256;
  const int egrid = (ET + TB - 1)/TB;

  // W transposes (bf16 [n][k]) — single launch
  wt_all_kernel<<<dim3(8,8,3), 256, 0, stream>>>(W1, W2, W3, Wt1, Wt2, Wt3);

  // scan-free CSR by destination (rebuilt every call; ws re-poisoned per launch)
  hipMemsetAsync(deg, 0, (size_t)(N+1)*4, stream);
  count_kernel<<<(E+TB-1)/TB, TB, 0, stream>>>(ei, deg, E);
  assign_kernel<<<(N+TB-1)/TB, TB, 0, stream>>>(deg, off, cursor, total, N);
  fill_kernel<<<egrid, TB, 0, stream>>>(ei, cursor, csr_src, E, N);

  // ---- layer 1: x(f32) @ W1, H=4, ELU ----
  gemm_mfma_kernel<256,false><<<(N+63)/64, 256, 0, stream>>>(x, Wt1, hB8, a1s, a1d, als, ald, N);
  aggregate4_kernel<true><<<N, 64, 0, stream>>>(hB8, als, ald, off, deg, csr_src, b1, hA);

  // ---- layer 2: hA(bf16) @ W2, H=4, ELU ----
  gemm_mfma_kernel<256,true><<<(N+63)/64, 256, 0, stream>>>(hA, Wt2, hB8, a2s, a2d, als, ald, N);
  aggregate4_kernel<true><<<N, 64, 0, stream>>>(hB8, als, ald, off, deg, csr_src, b2, hA);

  // ---- layer 3: hA(bf16) @ W3, H=1, no ELU ----
  gemm_mfma_kernel<64,true><<<(N+255)/256, 256, 0, stream>>>(hA, Wt3, h3, a3s, a3d, als, ald, N);
  aggregate1_kernel<<<N, 64, 0, stream>>>(h3, als, ald, off, deg, csr_src, b3, hA);

  // ---- pool + VAE head ----
  hipMemsetAsync(psum, 0, 64*64*4 + 64*4, stream);
  const int PBLK = 512;
  const int chunk = (N + PBLK - 1)/PBLK;
  pool_kernel<<<PBLK, 64, 0, stream>>>(hA, batch, psum, pcnt, N, chunk);
  head_kernel<<<64, 64, 0, stream>>>(psum, pcnt, Wmu, bmu, Wlv, blv, out);
}